// Round 2
// baseline (1272.538 us; speedup 1.0000x reference)
//
#include <hip/hip_runtime.h>
#include <hip/hip_bf16.h>
#include <math.h>

// ---- problem constants ----
#define D_MODEL 2048
#define SEQ     2048
#define BATCH   2
#define NHEAD   16
#define DK      128
#define DFF     8192
#define MROWS   (BATCH*SEQ)   // 4096 rows

typedef short short8 __attribute__((ext_vector_type(8)));   // 8 bf16 in 4 VGPRs
typedef float f32x4  __attribute__((ext_vector_type(4)));

__device__ __forceinline__ short f2bf(float f) {
  union { __hip_bfloat16 b; short s; } u;
  u.b = __float2bfloat16(f);
  return u.s;
}

// ---------------- RMSNorm: fp32 in -> bf16 out ----------------
__global__ __launch_bounds__(256) void rmsnorm_k(const float* __restrict__ x,
                                                 const float* __restrict__ g,
                                                 short* __restrict__ o) {
  const int row = blockIdx.x;
  const int t = threadIdx.x;
  const float4* xr = (const float4*)(x + (size_t)row * D_MODEL);
  const float4* gr = (const float4*)g;
  float4 v0 = xr[2*t], v1 = xr[2*t+1];
  float s = v0.x*v0.x + v0.y*v0.y + v0.z*v0.z + v0.w*v0.w
          + v1.x*v1.x + v1.y*v1.y + v1.z*v1.z + v1.w*v1.w;
  #pragma unroll
  for (int off = 1; off < 64; off <<= 1) s += __shfl_xor(s, off);
  __shared__ float red[4];
  if ((t & 63) == 0) red[t >> 6] = s;
  __syncthreads();
  float tot = red[0] + red[1] + red[2] + red[3];
  float inv = rsqrtf(tot * (1.0f / D_MODEL) + 1e-5f);
  float4 g0 = gr[2*t], g1v = gr[2*t+1];
  short8 ov;
  ov[0] = f2bf(v0.x * inv * g0.x);
  ov[1] = f2bf(v0.y * inv * g0.y);
  ov[2] = f2bf(v0.z * inv * g0.z);
  ov[3] = f2bf(v0.w * inv * g0.w);
  ov[4] = f2bf(v1.x * inv * g1v.x);
  ov[5] = f2bf(v1.y * inv * g1v.y);
  ov[6] = f2bf(v1.z * inv * g1v.z);
  ov[7] = f2bf(v1.w * inv * g1v.w);
  *((short8*)(o + (size_t)row * D_MODEL) + t) = ov;
}

// ---------------- GEMM: C[M,N] = A[M,K](bf16) * B[N,K](fp32->bf16)^T ----------------
// EPI: 0 = store bf16; 1 = exact GELU -> bf16; 2 = +resid -> fp32
template<int EPI>
__global__ __launch_bounds__(256) void gemm_bt(const short* __restrict__ A,
                                               const float* __restrict__ B,
                                               void* Cv,
                                               const float* resid,
                                               int M, int N, int K) {
  __shared__ __align__(16) short As[128][72];  // +8 pad: 144B row stride (16B mult)
  __shared__ __align__(16) short Bs[128][72];
  const int t = threadIdx.x;
  const int m0 = blockIdx.x * 128, n0 = blockIdx.y * 128;
  const int wave = t >> 6, lane = t & 63, lr = lane & 15, lg = lane >> 4;
  const int wr = (wave >> 1) * 64, wc = (wave & 1) * 64;

  f32x4 acc[4][4];
  const f32x4 z4 = {0.f, 0.f, 0.f, 0.f};
  #pragma unroll
  for (int m = 0; m < 4; ++m)
    #pragma unroll
    for (int n = 0; n < 4; ++n) acc[m][n] = z4;

  int ar[4], ac[4];
  #pragma unroll
  for (int i = 0; i < 4; ++i) { int u = t + 256*i; ar[i] = u >> 3; ac[i] = (u & 7) * 8; }

  for (int k0 = 0; k0 < K; k0 += 64) {
    // stage A (bf16 source)
    #pragma unroll
    for (int i = 0; i < 4; ++i) {
      uint4 va = *(const uint4*)(A + (size_t)(m0 + ar[i]) * K + k0 + ac[i]);
      *(uint4*)&As[ar[i]][ac[i]] = va;
    }
    // stage B (fp32 source, convert to bf16)
    #pragma unroll
    for (int i = 0; i < 4; ++i) {
      const float4* bp = (const float4*)(B + (size_t)(n0 + ar[i]) * K + k0 + ac[i]);
      float4 b0 = bp[0], b1 = bp[1];
      short8 pb = { f2bf(b0.x), f2bf(b0.y), f2bf(b0.z), f2bf(b0.w),
                    f2bf(b1.x), f2bf(b1.y), f2bf(b1.z), f2bf(b1.w) };
      *(short8*)&Bs[ar[i]][ac[i]] = pb;
    }
    __syncthreads();
    #pragma unroll
    for (int kk = 0; kk < 64; kk += 32) {
      short8 af[4], bf[4];
      #pragma unroll
      for (int m = 0; m < 4; ++m) af[m] = *(const short8*)&As[wr + m*16 + lr][kk + lg*8];
      #pragma unroll
      for (int n = 0; n < 4; ++n) bf[n] = *(const short8*)&Bs[wc + n*16 + lr][kk + lg*8];
      #pragma unroll
      for (int m = 0; m < 4; ++m)
        #pragma unroll
        for (int n = 0; n < 4; ++n)
          acc[m][n] = __builtin_amdgcn_mfma_f32_16x16x32_bf16(af[m], bf[n], acc[m][n], 0, 0, 0);
    }
    __syncthreads();
  }

  #pragma unroll
  for (int m = 0; m < 4; ++m)
    #pragma unroll
    for (int n = 0; n < 4; ++n)
      #pragma unroll
      for (int r = 0; r < 4; ++r) {
        int row = m0 + wr + m*16 + lg*4 + r;
        int col = n0 + wc + n*16 + lr;
        size_t idx = (size_t)row * N + col;
        float vv = acc[m][n][r];
        if (EPI == 0) {
          ((short*)Cv)[idx] = f2bf(vv);
        } else if (EPI == 1) {
          float gl = 0.5f * vv * (1.0f + erff(vv * 0.70710678118654752f));
          ((short*)Cv)[idx] = f2bf(gl);
        } else {
          ((float*)Cv)[idx] = vv + resid[idx];
        }
      }
}

// ---------------- Flash attention (causal), bf16 QKV, bf16 out ----------------
// grid: (SEQ/128, BATCH*NHEAD), 256 threads (4 waves x 32 q-rows)
__global__ __launch_bounds__(256) void attn_k(const short* __restrict__ Q,
                                              const short* __restrict__ K,
                                              const short* __restrict__ V,
                                              short* __restrict__ O) {
  const float scale = 0.08838834764831845f;  // 1/sqrt(128)
  const int qt = blockIdx.x;
  const int bh = blockIdx.y;
  const int b = bh >> 4, h = bh & 15;
  const size_t base = ((size_t)b * SEQ) * D_MODEL + (size_t)h * DK;
  const int t = threadIdx.x, wave = t >> 6, lane = t & 63, lr = lane & 15, lg = lane >> 4;

  __shared__ __align__(16) short Ks[32][136];   // 272B stride
  __shared__ __align__(16) short Vt[128][40];   // transposed V, 80B stride
  __shared__ __align__(16) short Ps[4][32][40]; // per-wave P tile

  const int qrow0 = qt * 128 + wave * 32;
  short8 qf[2][4];
  #pragma unroll
  for (int mq = 0; mq < 2; ++mq)
    #pragma unroll
    for (int ki = 0; ki < 4; ++ki)
      qf[mq][ki] = *(const short8*)(Q + base + (size_t)(qrow0 + mq*16 + lr) * D_MODEL + ki*32 + lg*8);

  f32x4 acc[2][8];
  const f32x4 z4 = {0.f, 0.f, 0.f, 0.f};
  #pragma unroll
  for (int mq = 0; mq < 2; ++mq)
    #pragma unroll
    for (int nd = 0; nd < 8; ++nd) acc[mq][nd] = z4;
  float mrow[2][4], lsum[2][4];
  #pragma unroll
  for (int mq = 0; mq < 2; ++mq)
    #pragma unroll
    for (int r = 0; r < 4; ++r) { mrow[mq][r] = -INFINITY; lsum[mq][r] = 0.f; }

  const int lastt = qt * 4 + 3;
  for (int tt = 0; tt <= lastt; ++tt) {
    // stage K tile + transposed V tile (kv rows tt*32 .. +31)
    #pragma unroll
    for (int i = 0; i < 2; ++i) {
      int u = t + 256*i; int r = u >> 4; int c = (u & 15) * 8;
      *(uint4*)&Ks[r][c] = *(const uint4*)(K + base + (size_t)(tt*32 + r) * D_MODEL + c);
      uint4 vv = *(const uint4*)(V + base + (size_t)(tt*32 + r) * D_MODEL + c);
      const short* sv = (const short*)&vv;
      #pragma unroll
      for (int j = 0; j < 8; ++j) Vt[c + j][r] = sv[j];
    }
    __syncthreads();
    if (tt <= qt * 4 + wave) {
      // S = Q K^T  (2 q-frags x 2 kv-frags)
      f32x4 sf[2][2] = {{z4, z4}, {z4, z4}};
      #pragma unroll
      for (int ki = 0; ki < 4; ++ki) {
        short8 kf0 = *(const short8*)&Ks[lr][ki*32 + lg*8];
        short8 kf1 = *(const short8*)&Ks[16 + lr][ki*32 + lg*8];
        sf[0][0] = __builtin_amdgcn_mfma_f32_16x16x32_bf16(qf[0][ki], kf0, sf[0][0], 0, 0, 0);
        sf[0][1] = __builtin_amdgcn_mfma_f32_16x16x32_bf16(qf[0][ki], kf1, sf[0][1], 0, 0, 0);
        sf[1][0] = __builtin_amdgcn_mfma_f32_16x16x32_bf16(qf[1][ki], kf0, sf[1][0], 0, 0, 0);
        sf[1][1] = __builtin_amdgcn_mfma_f32_16x16x32_bf16(qf[1][ki], kf1, sf[1][1], 0, 0, 0);
      }
      // online softmax (row = lg*4+r, cols = nk*16+lr across the 16-lane group)
      #pragma unroll
      for (int mq = 0; mq < 2; ++mq) {
        #pragma unroll
        for (int r = 0; r < 4; ++r) {
          int qg = qrow0 + mq*16 + lg*4 + r;
          float s0 = sf[mq][0][r] * scale;
          float s1 = sf[mq][1][r] * scale;
          if (tt*32 + lr > qg)       s0 = -INFINITY;
          if (tt*32 + 16 + lr > qg)  s1 = -INFINITY;
          float mx = fmaxf(s0, s1);
          mx = fmaxf(mx, __shfl_xor(mx, 1));
          mx = fmaxf(mx, __shfl_xor(mx, 2));
          mx = fmaxf(mx, __shfl_xor(mx, 4));
          mx = fmaxf(mx, __shfl_xor(mx, 8));
          float mnew = fmaxf(mrow[mq][r], mx);
          float alpha = __expf(mrow[mq][r] - mnew);
          mrow[mq][r] = mnew;
          float p0 = __expf(s0 - mnew);
          float p1 = __expf(s1 - mnew);
          float ps = p0 + p1;
          ps += __shfl_xor(ps, 1);
          ps += __shfl_xor(ps, 2);
          ps += __shfl_xor(ps, 4);
          ps += __shfl_xor(ps, 8);
          lsum[mq][r] = lsum[mq][r] * alpha + ps;
          #pragma unroll
          for (int nd = 0; nd < 8; ++nd) acc[mq][nd][r] *= alpha;
          Ps[wave][mq*16 + lg*4 + r][lr]      = f2bf(p0);
          Ps[wave][mq*16 + lg*4 + r][16 + lr] = f2bf(p1);
        }
      }
      asm volatile("s_waitcnt lgkmcnt(0)" ::: "memory");
      // O += P V   (A = P 32x32, B = V^T via Vt)
      short8 pf0 = *(const short8*)&Ps[wave][lr][lg*8];
      short8 pf1 = *(const short8*)&Ps[wave][16 + lr][lg*8];
      #pragma unroll
      for (int nd = 0; nd < 8; ++nd) {
        short8 vf = *(const short8*)&Vt[nd*16 + lr][lg*8];
        acc[0][nd] = __builtin_amdgcn_mfma_f32_16x16x32_bf16(pf0, vf, acc[0][nd], 0, 0, 0);
        acc[1][nd] = __builtin_amdgcn_mfma_f32_16x16x32_bf16(pf1, vf, acc[1][nd], 0, 0, 0);
      }
    }
    __syncthreads();
  }

  #pragma unroll
  for (int mq = 0; mq < 2; ++mq)
    #pragma unroll
    for (int nd = 0; nd < 8; ++nd)
      #pragma unroll
      for (int r = 0; r < 4; ++r) {
        int row = qrow0 + mq*16 + lg*4 + r;
        O[base + (size_t)row * D_MODEL + nd*16 + lr] = f2bf(acc[mq][nd][r] / lsum[mq][r]);
      }
}

// ---------------- launch ----------------
extern "C" void kernel_launch(void* const* d_in, const int* in_sizes, int n_in,
                              void* d_out, int out_size, void* d_ws, size_t ws_size,
                              hipStream_t stream) {
  const float* x  = (const float*)d_in[0];
  const float* wq = (const float*)d_in[1];
  const float* wk = (const float*)d_in[2];
  const float* wv = (const float*)d_in[3];
  const float* wo = (const float*)d_in[4];
  const float* w1 = (const float*)d_in[5];
  const float* w2 = (const float*)d_in[6];
  const float* g1 = (const float*)d_in[7];
  const float* g2 = (const float*)d_in[8];
  float* out = (float*)d_out;
  char* ws = (char*)d_ws;

  // ws layout (80 MiB total). Each of q/k/v/attn-out/xn is 4096x2048 bf16 = 16 MiB.
  //   [0,16M)  q          (later: FFN hidden half, 32 MiB at [0,32M))
  //   [16,32M) k
  //   [32,48M) v
  //   [48,64M) attn-out   (consumed by o-proj before FFN runs)
  //   [64,80M) xn (rmsnorm output, reused for both norms)
  short* qb = (short*)(ws + ((size_t)0  << 20));
  short* kb = (short*)(ws + ((size_t)16 << 20));
  short* vb = (short*)(ws + ((size_t)32 << 20));
  short* ab = (short*)(ws + ((size_t)48 << 20));
  short* xn = (short*)(ws + ((size_t)64 << 20));
  short* hb = (short*)(ws + ((size_t)0  << 20));  // 2048x8192 bf16 = 32 MiB per half

  dim3 gproj(MROWS / 128, D_MODEL / 128);

  // xn1 = rmsnorm(x, g1)
  rmsnorm_k<<<MROWS, 256, 0, stream>>>(x, g1, xn);
  // q,k,v projections
  gemm_bt<0><<<gproj, 256, 0, stream>>>(xn, wq, qb, nullptr, MROWS, D_MODEL, D_MODEL);
  gemm_bt<0><<<gproj, 256, 0, stream>>>(xn, wk, kb, nullptr, MROWS, D_MODEL, D_MODEL);
  gemm_bt<0><<<gproj, 256, 0, stream>>>(xn, wv, vb, nullptr, MROWS, D_MODEL, D_MODEL);
  // causal attention
  attn_k<<<dim3(SEQ / 128, BATCH * NHEAD), 256, 0, stream>>>(qb, kb, vb, ab);
  // x2 = x + attn @ wo^T   -> d_out (fp32)
  gemm_bt<2><<<gproj, 256, 0, stream>>>(ab, wo, out, x, MROWS, D_MODEL, D_MODEL);
  // xn2 = rmsnorm(x2, g2)
  rmsnorm_k<<<MROWS, 256, 0, stream>>>(out, g2, xn);
  // FFN in two M-halves so the 32 MiB hidden buffer fits in [0,32M)
  for (int half = 0; half < 2; ++half) {
    const short* xh = xn  + (size_t)half * 2048 * D_MODEL;
    float*       oh = out + (size_t)half * 2048 * D_MODEL;
    // h = gelu(xn2_half @ w1^T)
    gemm_bt<1><<<dim3(2048 / 128, DFF / 128), 256, 0, stream>>>(xh, w1, hb, nullptr, 2048, DFF, D_MODEL);
    // out_half = x2_half + h @ w2^T   (in-place residual on d_out)
    gemm_bt<2><<<dim3(2048 / 128, D_MODEL / 128), 256, 0, stream>>>(hb, w2, oh, oh, 2048, D_MODEL, DFF);
  }
}

// Round 3
// 1067.497 us; speedup vs baseline: 1.1921x; 1.1921x over previous
//
#include <hip/hip_runtime.h>
#include <hip/hip_bf16.h>
#include <math.h>

// ---- problem constants ----
#define D_MODEL 2048
#define SEQ     2048
#define BATCH   2
#define NHEAD   16
#define DK      128
#define DFF     8192
#define MROWS   (BATCH*SEQ)   // 4096 rows

typedef short short8 __attribute__((ext_vector_type(8)));   // 8 bf16 in 4 VGPRs
typedef float f32x4  __attribute__((ext_vector_type(4)));

__device__ __forceinline__ short f2bf(float f) {
  union { __hip_bfloat16 b; short s; } u;
  u.b = __float2bfloat16(f);
  return u.s;
}

__device__ __forceinline__ void gload_lds16(const void* g, void* l) {
  __builtin_amdgcn_global_load_lds(
      (const __attribute__((address_space(1))) unsigned int*)g,
      (__attribute__((address_space(3))) unsigned int*)l, 16, 0, 0);
}

// ---------------- RMSNorm: fp32 in -> bf16 out ----------------
__global__ __launch_bounds__(256) void rmsnorm_k(const float* __restrict__ x,
                                                 const float* __restrict__ g,
                                                 short* __restrict__ o) {
  const int row = blockIdx.x;
  const int t = threadIdx.x;
  const float4* xr = (const float4*)(x + (size_t)row * D_MODEL);
  const float4* gr = (const float4*)g;
  float4 v0 = xr[2*t], v1 = xr[2*t+1];
  float s = v0.x*v0.x + v0.y*v0.y + v0.z*v0.z + v0.w*v0.w
          + v1.x*v1.x + v1.y*v1.y + v1.z*v1.z + v1.w*v1.w;
  #pragma unroll
  for (int off = 1; off < 64; off <<= 1) s += __shfl_xor(s, off);
  __shared__ float red[4];
  if ((t & 63) == 0) red[t >> 6] = s;
  __syncthreads();
  float tot = red[0] + red[1] + red[2] + red[3];
  float inv = rsqrtf(tot * (1.0f / D_MODEL) + 1e-5f);
  float4 g0 = gr[2*t], g1v = gr[2*t+1];
  short8 ov;
  ov[0] = f2bf(v0.x * inv * g0.x);
  ov[1] = f2bf(v0.y * inv * g0.y);
  ov[2] = f2bf(v0.z * inv * g0.z);
  ov[3] = f2bf(v0.w * inv * g0.w);
  ov[4] = f2bf(v1.x * inv * g1v.x);
  ov[5] = f2bf(v1.y * inv * g1v.y);
  ov[6] = f2bf(v1.z * inv * g1v.z);
  ov[7] = f2bf(v1.w * inv * g1v.w);
  *((short8*)(o + (size_t)row * D_MODEL) + t) = ov;
}

// ---------------- fp32 -> bf16 convert (weights, one-time) ----------------
__global__ __launch_bounds__(256) void f2b_k(const float* __restrict__ src,
                                             short* __restrict__ dst, int n8) {
  int i = blockIdx.x * 256 + threadIdx.x;
  if (i >= n8) return;
  const float4* s4 = (const float4*)src + 2 * (size_t)i;
  float4 a = s4[0], b = s4[1];
  short8 o = { f2bf(a.x), f2bf(a.y), f2bf(a.z), f2bf(a.w),
               f2bf(b.x), f2bf(b.y), f2bf(b.z), f2bf(b.w) };
  *((short8*)dst + i) = o;
}

// ======== FAST PATH: m97-structure GEMM, bf16 A and B, global_load_lds ========
// C[M,N] = A[M,K] * B[N,K]^T ; EPI: 0 = bf16 store; 1 = exact GELU -> bf16; 2 = +resid -> fp32
template<int EPI>
__global__ __launch_bounds__(256) void gemm_fast(const short* __restrict__ A,
                                                 const short* __restrict__ B,
                                                 void* Cv,
                                                 const float* __restrict__ resid,
                                                 int M, int N, int K) {
  __shared__ __align__(16) short As[128 * 64];   // linear (global_load_lds dest)
  __shared__ __align__(16) short Bs[128 * 64];
  const int t = threadIdx.x;
  const int m0 = blockIdx.x * 128, n0 = blockIdx.y * 128;
  const int wave = t >> 6, lane = t & 63, lr = lane & 15, lg = lane >> 4;
  const int wr = (wave >> 1) * 64, wc = (wave & 1) * 64;

  f32x4 acc[4][4];
  const f32x4 z4 = {0.f, 0.f, 0.f, 0.f};
  #pragma unroll
  for (int m = 0; m < 4; ++m)
    #pragma unroll
    for (int n = 0; n < 4; ++n) acc[m][n] = z4;

  const int srow = t >> 3;          // 0..31, +32*i
  const int scol = (t & 7) * 8;     // shorts

  for (int k0 = 0; k0 < K; k0 += 64) {
    #pragma unroll
    for (int i = 0; i < 4; ++i) {
      int r = srow + 32 * i;
      gload_lds16(A + (size_t)(m0 + r) * K + k0 + scol, &As[r * 64 + scol]);
      gload_lds16(B + (size_t)(n0 + r) * K + k0 + scol, &Bs[r * 64 + scol]);
    }
    __syncthreads();
    #pragma unroll
    for (int kk = 0; kk < 64; kk += 32) {
      short8 af[4], bfr[4];
      #pragma unroll
      for (int m = 0; m < 4; ++m) af[m]  = *(const short8*)&As[(wr + m*16 + lr) * 64 + kk + lg*8];
      #pragma unroll
      for (int n = 0; n < 4; ++n) bfr[n] = *(const short8*)&Bs[(wc + n*16 + lr) * 64 + kk + lg*8];
      #pragma unroll
      for (int m = 0; m < 4; ++m)
        #pragma unroll
        for (int n = 0; n < 4; ++n)
          acc[m][n] = __builtin_amdgcn_mfma_f32_16x16x32_bf16(af[m], bfr[n], acc[m][n], 0, 0, 0);
    }
    __syncthreads();
  }

  #pragma unroll
  for (int m = 0; m < 4; ++m)
    #pragma unroll
    for (int n = 0; n < 4; ++n)
      #pragma unroll
      for (int r = 0; r < 4; ++r) {
        int row = m0 + wr + m*16 + lg*4 + r;
        int col = n0 + wc + n*16 + lr;
        size_t idx = (size_t)row * N + col;
        float vv = acc[m][n][r];
        if (EPI == 0) {
          ((short*)Cv)[idx] = f2bf(vv);
        } else if (EPI == 1) {
          float gl = 0.5f * vv * (1.0f + erff(vv * 0.70710678118654752f));
          ((short*)Cv)[idx] = f2bf(gl);
        } else {
          ((float*)Cv)[idx] = vv + resid[idx];
        }
      }
}

// ---------------- V transpose: qkv[.., v cols] -> vt[b][h][d][s] ----------------
__global__ __launch_bounds__(256) void vtrans(const short* __restrict__ QKV,
                                              short* __restrict__ VT) {
  const int st = blockIdx.x;   // s tile of 64
  const int bh = blockIdx.y;
  const int b = bh >> 4, h = bh & 15;
  const int t = threadIdx.x;
  __shared__ __align__(16) short T[64 * 128];
  const short* Vsrc = QKV + ((size_t)b * SEQ) * 6144 + 2 * D_MODEL + h * DK;
  {
    int r = t >> 4, c = (t & 15) * 8;
    #pragma unroll
    for (int i = 0; i < 4; ++i) {
      int rr = r + 16 * i;
      uint4 vv = *(const uint4*)(Vsrc + (size_t)(st * 64 + rr) * 6144 + c);
      *(uint4*)&T[rr * 128 + (c ^ (((rr >> 3) & 7) << 3))] = vv;
    }
  }
  __syncthreads();
  short* dst = VT + ((size_t)bh * DK) * SEQ + st * 64;
  {
    int c2 = (t & 7) * 8;
    #pragma unroll
    for (int i = 0; i < 4; ++i) {
      int d = (t >> 3) + 32 * i;
      short8 ov;
      #pragma unroll
      for (int j = 0; j < 8; ++j)
        ov[j] = T[(c2 + j) * 128 + (d ^ ((((c2 + j) >> 3) & 7) << 3))];
      *(short8*)(dst + (size_t)d * SEQ + c2) = ov;
    }
  }
}

// ---------------- Flash attention v2: KV tile 64, swizzled LDS ----------------
// grid (SEQ/64, BATCH*NHEAD), 256 threads = 4 waves x 16 q-rows
__global__ __launch_bounds__(256) void attn2(const short* __restrict__ QKV,
                                             const short* __restrict__ VT,
                                             short* __restrict__ O) {
  const float SC = 0.12751743f;   // (1/sqrt(128)) * log2(e)
  const int qt = blockIdx.x, bh = blockIdx.y;
  const int b = bh >> 4, h = bh & 15;
  const int t = threadIdx.x, w = t >> 6, lane = t & 63, lr = lane & 15, lg = lane >> 4;
  const short* Qp = QKV + ((size_t)b * SEQ) * 6144 + h * DK;
  const short* Kp = Qp + D_MODEL;
  const short* Vp = VT + ((size_t)bh * DK) * SEQ;   // [d][s]
  __shared__ __align__(16) short Ks[64 * 128];      // swizzled: ^ (row&7)<<3 shorts
  __shared__ __align__(16) short Vs[128 * 64];
  __shared__ __align__(16) short Ps[4][16][72];

  const int qrow0 = qt * 64 + w * 16;
  short8 qf[4];
  #pragma unroll
  for (int ki = 0; ki < 4; ++ki)
    qf[ki] = *(const short8*)(Qp + (size_t)(qrow0 + lr) * 6144 + ki * 32 + lg * 8);

  f32x4 acc[8];
  const f32x4 z4 = {0.f, 0.f, 0.f, 0.f};
  #pragma unroll
  for (int nd = 0; nd < 8; ++nd) acc[nd] = z4;
  float mrow[4], lsum[4];
  #pragma unroll
  for (int r = 0; r < 4; ++r) { mrow[r] = -INFINITY; lsum[r] = 0.f; }

  const int kr = t >> 4, kc = (t & 15) * 8;   // K stage: rows kr+16i, cols kc
  const int vd = t >> 3, vc = (t & 7) * 8;    // V stage: rows vd+32i (d), cols vc (s)

  for (int tt = 0; tt <= qt; ++tt) {
    #pragma unroll
    for (int i = 0; i < 4; ++i) {
      int r = kr + 16 * i;
      uint4 kvv = *(const uint4*)(Kp + (size_t)(tt * 64 + r) * 6144 + kc);
      *(uint4*)&Ks[(r * 128 + kc) ^ ((r & 7) << 3)] = kvv;
      int d = vd + 32 * i;
      uint4 vvv = *(const uint4*)(Vp + (size_t)d * SEQ + tt * 64 + vc);
      *(uint4*)&Vs[(d * 64 + vc) ^ ((d & 7) << 3)] = vvv;
    }
    __syncthreads();

    // S = Q K^T  (16 q-rows x 64 kv)
    f32x4 sf[4] = {z4, z4, z4, z4};
    #pragma unroll
    for (int ki = 0; ki < 4; ++ki) {
      #pragma unroll
      for (int nk = 0; nk < 4; ++nk) {
        int rr = nk * 16 + lr;
        short8 kf = *(const short8*)&Ks[(rr * 128 + ki * 32 + lg * 8) ^ ((rr & 7) << 3)];
        sf[nk] = __builtin_amdgcn_mfma_f32_16x16x32_bf16(qf[ki], kf, sf[nk], 0, 0, 0);
      }
    }

    const bool diag = (tt == qt);
    #pragma unroll
    for (int r = 0; r < 4; ++r) {
      int qg = qrow0 + lg * 4 + r;
      float s0 = sf[0][r] * SC, s1 = sf[1][r] * SC, s2 = sf[2][r] * SC, s3 = sf[3][r] * SC;
      if (diag) {
        int c0 = tt * 64 + lr;
        s0 = (c0      <= qg) ? s0 : -3.0e38f;
        s1 = (c0 + 16 <= qg) ? s1 : -3.0e38f;
        s2 = (c0 + 32 <= qg) ? s2 : -3.0e38f;
        s3 = (c0 + 48 <= qg) ? s3 : -3.0e38f;
      }
      float mx = fmaxf(fmaxf(s0, s1), fmaxf(s2, s3));
      mx = fmaxf(mx, __shfl_xor(mx, 1));
      mx = fmaxf(mx, __shfl_xor(mx, 2));
      mx = fmaxf(mx, __shfl_xor(mx, 4));
      mx = fmaxf(mx, __shfl_xor(mx, 8));
      float mnew = fmaxf(mrow[r], mx);
      float alpha = exp2f(mrow[r] - mnew);
      mrow[r] = mnew;
      float p0 = exp2f(s0 - mnew), p1 = exp2f(s1 - mnew),
            p2 = exp2f(s2 - mnew), p3 = exp2f(s3 - mnew);
      float ps = (p0 + p1) + (p2 + p3);
      ps += __shfl_xor(ps, 1);
      ps += __shfl_xor(ps, 2);
      ps += __shfl_xor(ps, 4);
      ps += __shfl_xor(ps, 8);
      lsum[r] = lsum[r] * alpha + ps;
      #pragma unroll
      for (int nd = 0; nd < 8; ++nd) acc[nd][r] *= alpha;
      short* pr = &Ps[w][lg * 4 + r][0];
      pr[lr]      = f2bf(p0);
      pr[16 + lr] = f2bf(p1);
      pr[32 + lr] = f2bf(p2);
      pr[48 + lr] = f2bf(p3);
    }
    asm volatile("s_waitcnt lgkmcnt(0)" ::: "memory");
    __builtin_amdgcn_sched_barrier(0);

    // O += P V  (A = P 16x64 via Ps, B^T = V^T via Vs)
    short8 pf0 = *(const short8*)&Ps[w][lr][lg * 8];
    short8 pf1 = *(const short8*)&Ps[w][lr][32 + lg * 8];
    #pragma unroll
    for (int nd = 0; nd < 8; ++nd) {
      int rr = nd * 16 + lr;
      short8 vf0 = *(const short8*)&Vs[(rr * 64 + lg * 8) ^ ((rr & 7) << 3)];
      short8 vf1 = *(const short8*)&Vs[(rr * 64 + 32 + lg * 8) ^ ((rr & 7) << 3)];
      acc[nd] = __builtin_amdgcn_mfma_f32_16x16x32_bf16(pf0, vf0, acc[nd], 0, 0, 0);
      acc[nd] = __builtin_amdgcn_mfma_f32_16x16x32_bf16(pf1, vf1, acc[nd], 0, 0, 0);
    }
    __syncthreads();
  }

  #pragma unroll
  for (int nd = 0; nd < 8; ++nd)
    #pragma unroll
    for (int r = 0; r < 4; ++r) {
      int row = qrow0 + lg * 4 + r;
      O[(size_t)(b * SEQ + row) * D_MODEL + h * DK + nd * 16 + lr] = f2bf(acc[nd][r] / lsum[r]);
    }
}

// ======== FALLBACK PATH (round-2 verified kernels) ========
template<int EPI>
__global__ __launch_bounds__(256) void gemm_bt(const short* __restrict__ A,
                                               const float* __restrict__ B,
                                               void* Cv,
                                               const float* resid,
                                               int M, int N, int K) {
  __shared__ __align__(16) short As[128][72];
  __shared__ __align__(16) short Bs[128][72];
  const int t = threadIdx.x;
  const int m0 = blockIdx.x * 128, n0 = blockIdx.y * 128;
  const int wave = t >> 6, lane = t & 63, lr = lane & 15, lg = lane >> 4;
  const int wr = (wave >> 1) * 64, wc = (wave & 1) * 64;

  f32x4 acc[4][4];
  const f32x4 z4 = {0.f, 0.f, 0.f, 0.f};
  #pragma unroll
  for (int m = 0; m < 4; ++m)
    #pragma unroll
    for (int n = 0; n < 4; ++n) acc[m][n] = z4;

  int ar[4], ac[4];
  #pragma unroll
  for (int i = 0; i < 4; ++i) { int u = t + 256*i; ar[i] = u >> 3; ac[i] = (u & 7) * 8; }

  for (int k0 = 0; k0 < K; k0 += 64) {
    #pragma unroll
    for (int i = 0; i < 4; ++i) {
      uint4 va = *(const uint4*)(A + (size_t)(m0 + ar[i]) * K + k0 + ac[i]);
      *(uint4*)&As[ar[i]][ac[i]] = va;
    }
    #pragma unroll
    for (int i = 0; i < 4; ++i) {
      const float4* bp = (const float4*)(B + (size_t)(n0 + ar[i]) * K + k0 + ac[i]);
      float4 b0 = bp[0], b1 = bp[1];
      short8 pb = { f2bf(b0.x), f2bf(b0.y), f2bf(b0.z), f2bf(b0.w),
                    f2bf(b1.x), f2bf(b1.y), f2bf(b1.z), f2bf(b1.w) };
      *(short8*)&Bs[ar[i]][ac[i]] = pb;
    }
    __syncthreads();
    #pragma unroll
    for (int kk = 0; kk < 64; kk += 32) {
      short8 af[4], bfr[4];
      #pragma unroll
      for (int m = 0; m < 4; ++m) af[m]  = *(const short8*)&As[wr + m*16 + lr][kk + lg*8];
      #pragma unroll
      for (int n = 0; n < 4; ++n) bfr[n] = *(const short8*)&Bs[wc + n*16 + lr][kk + lg*8];
      #pragma unroll
      for (int m = 0; m < 4; ++m)
        #pragma unroll
        for (int n = 0; n < 4; ++n)
          acc[m][n] = __builtin_amdgcn_mfma_f32_16x16x32_bf16(af[m], bfr[n], acc[m][n], 0, 0, 0);
    }
    __syncthreads();
  }

  #pragma unroll
  for (int m = 0; m < 4; ++m)
    #pragma unroll
    for (int n = 0; n < 4; ++n)
      #pragma unroll
      for (int r = 0; r < 4; ++r) {
        int row = m0 + wr + m*16 + lg*4 + r;
        int col = n0 + wc + n*16 + lr;
        size_t idx = (size_t)row * N + col;
        float vv = acc[m][n][r];
        if (EPI == 0) {
          ((short*)Cv)[idx] = f2bf(vv);
        } else if (EPI == 1) {
          float gl = 0.5f * vv * (1.0f + erff(vv * 0.70710678118654752f));
          ((short*)Cv)[idx] = f2bf(gl);
        } else {
          ((float*)Cv)[idx] = vv + resid[idx];
        }
      }
}

__global__ __launch_bounds__(256) void attn_k(const short* __restrict__ Q,
                                              const short* __restrict__ K,
                                              const short* __restrict__ V,
                                              short* __restrict__ O) {
  const float scale = 0.08838834764831845f;
  const int qt = blockIdx.x;
  const int bh = blockIdx.y;
  const int b = bh >> 4, h = bh & 15;
  const size_t base = ((size_t)b * SEQ) * D_MODEL + (size_t)h * DK;
  const int t = threadIdx.x, wave = t >> 6, lane = t & 63, lr = lane & 15, lg = lane >> 4;

  __shared__ __align__(16) short Ks[32][136];
  __shared__ __align__(16) short Vt[128][40];
  __shared__ __align__(16) short Ps[4][32][40];

  const int qrow0 = qt * 128 + wave * 32;
  short8 qf[2][4];
  #pragma unroll
  for (int mq = 0; mq < 2; ++mq)
    #pragma unroll
    for (int ki = 0; ki < 4; ++ki)
      qf[mq][ki] = *(const short8*)(Q + base + (size_t)(qrow0 + mq*16 + lr) * D_MODEL + ki*32 + lg*8);

  f32x4 acc[2][8];
  const f32x4 z4 = {0.f, 0.f, 0.f, 0.f};
  #pragma unroll
  for (int mq = 0; mq < 2; ++mq)
    #pragma unroll
    for (int nd = 0; nd < 8; ++nd) acc[mq][nd] = z4;
  float mrow[2][4], lsum[2][4];
  #pragma unroll
  for (int mq = 0; mq < 2; ++mq)
    #pragma unroll
    for (int r = 0; r < 4; ++r) { mrow[mq][r] = -INFINITY; lsum[mq][r] = 0.f; }

  const int lastt = qt * 4 + 3;
  for (int tt = 0; tt <= lastt; ++tt) {
    #pragma unroll
    for (int i = 0; i < 2; ++i) {
      int u = t + 256*i; int r = u >> 4; int c = (u & 15) * 8;
      *(uint4*)&Ks[r][c] = *(const uint4*)(K + base + (size_t)(tt*32 + r) * D_MODEL + c);
      uint4 vv = *(const uint4*)(V + base + (size_t)(tt*32 + r) * D_MODEL + c);
      const short* sv = (const short*)&vv;
      #pragma unroll
      for (int j = 0; j < 8; ++j) Vt[c + j][r] = sv[j];
    }
    __syncthreads();
    if (tt <= qt * 4 + wave) {
      f32x4 sf[2][2] = {{z4, z4}, {z4, z4}};
      #pragma unroll
      for (int ki = 0; ki < 4; ++ki) {
        short8 kf0 = *(const short8*)&Ks[lr][ki*32 + lg*8];
        short8 kf1 = *(const short8*)&Ks[16 + lr][ki*32 + lg*8];
        sf[0][0] = __builtin_amdgcn_mfma_f32_16x16x32_bf16(qf[0][ki], kf0, sf[0][0], 0, 0, 0);
        sf[0][1] = __builtin_amdgcn_mfma_f32_16x16x32_bf16(qf[0][ki], kf1, sf[0][1], 0, 0, 0);
        sf[1][0] = __builtin_amdgcn_mfma_f32_16x16x32_bf16(qf[1][ki], kf0, sf[1][0], 0, 0, 0);
        sf[1][1] = __builtin_amdgcn_mfma_f32_16x16x32_bf16(qf[1][ki], kf1, sf[1][1], 0, 0, 0);
      }
      #pragma unroll
      for (int mq = 0; mq < 2; ++mq) {
        #pragma unroll
        for (int r = 0; r < 4; ++r) {
          int qg = qrow0 + mq*16 + lg*4 + r;
          float s0 = sf[mq][0][r] * scale;
          float s1 = sf[mq][1][r] * scale;
          if (tt*32 + lr > qg)       s0 = -INFINITY;
          if (tt*32 + 16 + lr > qg)  s1 = -INFINITY;
          float mx = fmaxf(s0, s1);
          mx = fmaxf(mx, __shfl_xor(mx, 1));
          mx = fmaxf(mx, __shfl_xor(mx, 2));
          mx = fmaxf(mx, __shfl_xor(mx, 4));
          mx = fmaxf(mx, __shfl_xor(mx, 8));
          float mnew = fmaxf(mrow[mq][r], mx);
          float alpha = __expf(mrow[mq][r] - mnew);
          mrow[mq][r] = mnew;
          float p0 = __expf(s0 - mnew);
          float p1 = __expf(s1 - mnew);
          float ps = p0 + p1;
          ps += __shfl_xor(ps, 1);
          ps += __shfl_xor(ps, 2);
          ps += __shfl_xor(ps, 4);
          ps += __shfl_xor(ps, 8);
          lsum[mq][r] = lsum[mq][r] * alpha + ps;
          #pragma unroll
          for (int nd = 0; nd < 8; ++nd) acc[mq][nd][r] *= alpha;
          Ps[wave][mq*16 + lg*4 + r][lr]      = f2bf(p0);
          Ps[wave][mq*16 + lg*4 + r][16 + lr] = f2bf(p1);
        }
      }
      asm volatile("s_waitcnt lgkmcnt(0)" ::: "memory");
      short8 pf0 = *(const short8*)&Ps[wave][lr][lg*8];
      short8 pf1 = *(const short8*)&Ps[wave][16 + lr][lg*8];
      #pragma unroll
      for (int nd = 0; nd < 8; ++nd) {
        short8 vf = *(const short8*)&Vt[nd*16 + lr][lg*8];
        acc[0][nd] = __builtin_amdgcn_mfma_f32_16x16x32_bf16(pf0, vf, acc[0][nd], 0, 0, 0);
        acc[1][nd] = __builtin_amdgcn_mfma_f32_16x16x32_bf16(pf1, vf, acc[1][nd], 0, 0, 0);
      }
    }
    __syncthreads();
  }

  #pragma unroll
  for (int mq = 0; mq < 2; ++mq)
    #pragma unroll
    for (int nd = 0; nd < 8; ++nd)
      #pragma unroll
      for (int r = 0; r < 4; ++r) {
        int row = qrow0 + mq*16 + lg*4 + r;
        O[base + (size_t)row * D_MODEL + nd*16 + lr] = f2bf(acc[mq][nd][r] / lsum[mq][r]);
      }
}

// ---------------- launch ----------------
extern "C" void kernel_launch(void* const* d_in, const int* in_sizes, int n_in,
                              void* d_out, int out_size, void* d_ws, size_t ws_size,
                              hipStream_t stream) {
  const float* x  = (const float*)d_in[0];
  const float* wq = (const float*)d_in[1];
  const float* wk = (const float*)d_in[2];
  const float* wv = (const float*)d_in[3];
  const float* wo = (const float*)d_in[4];
  const float* w1 = (const float*)d_in[5];
  const float* w2 = (const float*)d_in[6];
  const float* g1 = (const float*)d_in[7];
  const float* g2 = (const float*)d_in[8];
  float* out = (float*)d_out;
  char* ws = (char*)d_ws;

  const size_t NEED = (size_t)192 << 20;
  if (ws_size >= NEED) {
    // fast path layout (192 MiB):
    //   [0,24M)    wqkv bf16 [6144][2048]
    //   [24,32M)   wo bf16
    //   [32,64M)   w1 bf16
    //   [64,96M)   w2 bf16
    //   [96,144M)  qkv bf16 [4096][6144]   (dead after attn; hb overlaps)
    //   [144,160M) vt bf16 [32][128][2048] (dead after attn)
    //   [160,176M) attn-out bf16
    //   [176,192M) xn bf16
    //   [96,160M)  hb bf16 [4096][8192]    (FFN phase)
    short* wqkv = (short*)(ws);
    short* wo_b = (short*)(ws + ((size_t)24 << 20));
    short* w1_b = (short*)(ws + ((size_t)32 << 20));
    short* w2_b = (short*)(ws + ((size_t)64 << 20));
    short* qkv  = (short*)(ws + ((size_t)96 << 20));
    short* vt   = (short*)(ws + ((size_t)144 << 20));
    short* ab   = (short*)(ws + ((size_t)160 << 20));
    short* xn   = (short*)(ws + ((size_t)176 << 20));
    short* hb   = (short*)(ws + ((size_t)96 << 20));

    const int NW = D_MODEL * D_MODEL / 8;     // 524288 short8 per d_model^2 weight
    f2b_k<<<(NW + 255) / 256, 256, 0, stream>>>(wq, wqkv,                   NW);
    f2b_k<<<(NW + 255) / 256, 256, 0, stream>>>(wk, wqkv + (size_t)D_MODEL * D_MODEL,     NW);
    f2b_k<<<(NW + 255) / 256, 256, 0, stream>>>(wv, wqkv + (size_t)2 * D_MODEL * D_MODEL, NW);
    f2b_k<<<(NW + 255) / 256, 256, 0, stream>>>(wo, wo_b, NW);
    const int NF = DFF * D_MODEL / 8;
    f2b_k<<<(NF + 255) / 256, 256, 0, stream>>>(w1, w1_b, NF);
    f2b_k<<<(NF + 255) / 256, 256, 0, stream>>>(w2, w2_b, NF);

    rmsnorm_k<<<MROWS, 256, 0, stream>>>(x, g1, xn);
    gemm_fast<0><<<dim3(MROWS/128, 6144/128), 256, 0, stream>>>(xn, wqkv, qkv, nullptr, MROWS, 6144, D_MODEL);
    vtrans<<<dim3(SEQ/64, BATCH*NHEAD), 256, 0, stream>>>(qkv, vt);
    attn2<<<dim3(SEQ/64, BATCH*NHEAD), 256, 0, stream>>>(qkv, vt, ab);
    gemm_fast<2><<<dim3(MROWS/128, D_MODEL/128), 256, 0, stream>>>(ab, wo_b, out, x, MROWS, D_MODEL, D_MODEL);
    rmsnorm_k<<<MROWS, 256, 0, stream>>>(out, g2, xn);
    gemm_fast<1><<<dim3(MROWS/128, DFF/128), 256, 0, stream>>>(xn, w1_b, hb, nullptr, MROWS, DFF, D_MODEL);
    gemm_fast<2><<<dim3(MROWS/128, D_MODEL/128), 256, 0, stream>>>(hb, w2_b, out, out, MROWS, D_MODEL, DFF);
  } else {
    // fallback: round-2 verified path (80 MiB)
    short* qb = (short*)(ws + ((size_t)0  << 20));
    short* kb = (short*)(ws + ((size_t)16 << 20));
    short* vb = (short*)(ws + ((size_t)32 << 20));
    short* ab = (short*)(ws + ((size_t)48 << 20));
    short* xn = (short*)(ws + ((size_t)64 << 20));
    short* hb = (short*)(ws + ((size_t)0  << 20));

    dim3 gproj(MROWS / 128, D_MODEL / 128);
    rmsnorm_k<<<MROWS, 256, 0, stream>>>(x, g1, xn);
    gemm_bt<0><<<gproj, 256, 0, stream>>>(xn, wq, qb, nullptr, MROWS, D_MODEL, D_MODEL);
    gemm_bt<0><<<gproj, 256, 0, stream>>>(xn, wk, kb, nullptr, MROWS, D_MODEL, D_MODEL);
    gemm_bt<0><<<gproj, 256, 0, stream>>>(xn, wv, vb, nullptr, MROWS, D_MODEL, D_MODEL);
    attn_k<<<dim3(SEQ / 128, BATCH * NHEAD), 256, 0, stream>>>(qb, kb, vb, ab);
    gemm_bt<2><<<gproj, 256, 0, stream>>>(ab, wo, out, x, MROWS, D_MODEL, D_MODEL);
    rmsnorm_k<<<MROWS, 256, 0, stream>>>(out, g2, xn);
    for (int half = 0; half < 2; ++half) {
      const short* xh = xn  + (size_t)half * 2048 * D_MODEL;
      float*       oh = out + (size_t)half * 2048 * D_MODEL;
      gemm_bt<1><<<dim3(2048 / 128, DFF / 128), 256, 0, stream>>>(xh, w1, hb, nullptr, 2048, DFF, D_MODEL);
      gemm_bt<2><<<dim3(2048 / 128, D_MODEL / 128), 256, 0, stream>>>(hb, w2, oh, oh, 2048, D_MODEL, DFF);
    }
  }
}

// Round 4
// 917.068 us; speedup vs baseline: 1.3876x; 1.1640x over previous
//
#include <hip/hip_runtime.h>
#include <hip/hip_bf16.h>
#include <math.h>

// ---- problem constants ----
#define D_MODEL 2048
#define SEQ     2048
#define BATCH   2
#define NHEAD   16
#define DK      128
#define DFF     8192
#define MROWS   (BATCH*SEQ)   // 4096 rows

typedef short short8 __attribute__((ext_vector_type(8)));   // 8 bf16 in 4 VGPRs
typedef float f32x4  __attribute__((ext_vector_type(4)));

__device__ __forceinline__ short f2bf(float f) {
  union { __hip_bfloat16 b; short s; } u;
  u.b = __float2bfloat16(f);
  return u.s;
}

__device__ __forceinline__ void gload_lds16(const void* g, void* l) {
  __builtin_amdgcn_global_load_lds(
      (const __attribute__((address_space(1))) unsigned int*)g,
      (__attribute__((address_space(3))) unsigned int*)l, 16, 0, 0);
}

// ---------------- RMSNorm: fp32 in -> bf16 out ----------------
__global__ __launch_bounds__(256) void rmsnorm_k(const float* __restrict__ x,
                                                 const float* __restrict__ g,
                                                 short* __restrict__ o) {
  const int row = blockIdx.x;
  const int t = threadIdx.x;
  const float4* xr = (const float4*)(x + (size_t)row * D_MODEL);
  const float4* gr = (const float4*)g;
  float4 v0 = xr[2*t], v1 = xr[2*t+1];
  float s = v0.x*v0.x + v0.y*v0.y + v0.z*v0.z + v0.w*v0.w
          + v1.x*v1.x + v1.y*v1.y + v1.z*v1.z + v1.w*v1.w;
  #pragma unroll
  for (int off = 1; off < 64; off <<= 1) s += __shfl_xor(s, off);
  __shared__ float red[4];
  if ((t & 63) == 0) red[t >> 6] = s;
  __syncthreads();
  float tot = red[0] + red[1] + red[2] + red[3];
  float inv = rsqrtf(tot * (1.0f / D_MODEL) + 1e-5f);
  float4 g0 = gr[2*t], g1v = gr[2*t+1];
  short8 ov;
  ov[0] = f2bf(v0.x * inv * g0.x);
  ov[1] = f2bf(v0.y * inv * g0.y);
  ov[2] = f2bf(v0.z * inv * g0.z);
  ov[3] = f2bf(v0.w * inv * g0.w);
  ov[4] = f2bf(v1.x * inv * g1v.x);
  ov[5] = f2bf(v1.y * inv * g1v.y);
  ov[6] = f2bf(v1.z * inv * g1v.z);
  ov[7] = f2bf(v1.w * inv * g1v.w);
  *((short8*)(o + (size_t)row * D_MODEL) + t) = ov;
}

// ---------------- fp32 -> bf16 convert (weights, one-time) ----------------
__global__ __launch_bounds__(256) void f2b_k(const float* __restrict__ src,
                                             short* __restrict__ dst, int n8) {
  int i = blockIdx.x * 256 + threadIdx.x;
  if (i >= n8) return;
  const float4* s4 = (const float4*)src + 2 * (size_t)i;
  float4 a = s4[0], b = s4[1];
  short8 o = { f2bf(a.x), f2bf(a.y), f2bf(a.z), f2bf(a.w),
               f2bf(b.x), f2bf(b.y), f2bf(b.z), f2bf(b.w) };
  *((short8*)dst + i) = o;
}

// ======== FAST PATH: m97-structure GEMM, bf16 A and B, global_load_lds ========
// C[M,N] = A[M,K] * B[N,K]^T ; EPI: 0 = bf16 store; 1 = exact GELU -> bf16; 2 = +resid -> fp32
template<int EPI>
__global__ __launch_bounds__(256) void gemm_fast(const short* __restrict__ A,
                                                 const short* __restrict__ B,
                                                 void* Cv,
                                                 const float* __restrict__ resid,
                                                 int M, int N, int K) {
  __shared__ __align__(16) short As[128 * 64];   // linear (global_load_lds dest)
  __shared__ __align__(16) short Bs[128 * 64];
  const int t = threadIdx.x;
  const int m0 = blockIdx.x * 128, n0 = blockIdx.y * 128;
  const int wave = t >> 6, lane = t & 63, lr = lane & 15, lg = lane >> 4;
  const int wr = (wave >> 1) * 64, wc = (wave & 1) * 64;

  f32x4 acc[4][4];
  const f32x4 z4 = {0.f, 0.f, 0.f, 0.f};
  #pragma unroll
  for (int m = 0; m < 4; ++m)
    #pragma unroll
    for (int n = 0; n < 4; ++n) acc[m][n] = z4;

  const int srow = t >> 3;          // 0..31, +32*i
  const int scol = (t & 7) * 8;     // shorts

  for (int k0 = 0; k0 < K; k0 += 64) {
    #pragma unroll
    for (int i = 0; i < 4; ++i) {
      int r = srow + 32 * i;
      gload_lds16(A + (size_t)(m0 + r) * K + k0 + scol, &As[r * 64 + scol]);
      gload_lds16(B + (size_t)(n0 + r) * K + k0 + scol, &Bs[r * 64 + scol]);
    }
    __syncthreads();
    #pragma unroll
    for (int kk = 0; kk < 64; kk += 32) {
      short8 af[4], bfr[4];
      #pragma unroll
      for (int m = 0; m < 4; ++m) af[m]  = *(const short8*)&As[(wr + m*16 + lr) * 64 + kk + lg*8];
      #pragma unroll
      for (int n = 0; n < 4; ++n) bfr[n] = *(const short8*)&Bs[(wc + n*16 + lr) * 64 + kk + lg*8];
      #pragma unroll
      for (int m = 0; m < 4; ++m)
        #pragma unroll
        for (int n = 0; n < 4; ++n)
          acc[m][n] = __builtin_amdgcn_mfma_f32_16x16x32_bf16(af[m], bfr[n], acc[m][n], 0, 0, 0);
    }
    __syncthreads();
  }

  #pragma unroll
  for (int m = 0; m < 4; ++m)
    #pragma unroll
    for (int n = 0; n < 4; ++n)
      #pragma unroll
      for (int r = 0; r < 4; ++r) {
        int row = m0 + wr + m*16 + lg*4 + r;
        int col = n0 + wc + n*16 + lr;
        size_t idx = (size_t)row * N + col;
        float vv = acc[m][n][r];
        if (EPI == 0) {
          ((short*)Cv)[idx] = f2bf(vv);
        } else if (EPI == 1) {
          float gl = 0.5f * vv * (1.0f + erff(vv * 0.70710678118654752f));
          ((short*)Cv)[idx] = f2bf(gl);
        } else {
          ((float*)Cv)[idx] = vv + resid[idx];
        }
      }
}

// ---------------- V transpose: qkv[.., v cols] -> vt[b][h][d][s] ----------------
__global__ __launch_bounds__(256) void vtrans(const short* __restrict__ QKV,
                                              short* __restrict__ VT) {
  const int st = blockIdx.x;   // s tile of 64
  const int bh = blockIdx.y;
  const int b = bh >> 4, h = bh & 15;
  const int t = threadIdx.x;
  __shared__ __align__(16) short T[64 * 128];
  const short* Vsrc = QKV + ((size_t)b * SEQ) * 6144 + 2 * D_MODEL + h * DK;
  {
    int r = t >> 4, c = (t & 15) * 8;
    #pragma unroll
    for (int i = 0; i < 4; ++i) {
      int rr = r + 16 * i;
      uint4 vv = *(const uint4*)(Vsrc + (size_t)(st * 64 + rr) * 6144 + c);
      *(uint4*)&T[rr * 128 + (c ^ (((rr >> 3) & 7) << 3))] = vv;
    }
  }
  __syncthreads();
  short* dst = VT + ((size_t)bh * DK) * SEQ + st * 64;
  {
    int c2 = (t & 7) * 8;
    #pragma unroll
    for (int i = 0; i < 4; ++i) {
      int d = (t >> 3) + 32 * i;
      short8 ov;
      #pragma unroll
      for (int j = 0; j < 8; ++j)
        ov[j] = T[(c2 + j) * 128 + (d ^ ((((c2 + j) >> 3) & 7) << 3))];
      *(short8*)(dst + (size_t)d * SEQ + c2) = ov;
    }
  }
}

// ---------------- Flash attention v3 ----------------
// 8 waves (512 thr), block handles q-tile pair (a, 15-a) sequentially ->
// uniform 34 KV-iters/block; grid (8, 32) = 256 blocks = 1/CU.
// Double-buffered swizzled K/V LDS with async reg-staging; deferred lsum reduce.
__global__ __launch_bounds__(512, 2) void attn3(const short* __restrict__ QKV,
                                                const short* __restrict__ VT,
                                                short* __restrict__ O) {
  const float SC = 0.12751743f;   // (1/sqrt(128)) * log2(e)
  const int a = blockIdx.x, bh = blockIdx.y;
  const int b = bh >> 4, h = bh & 15;
  const int t = threadIdx.x, w = t >> 6, lane = t & 63, lr = lane & 15, lg = lane >> 4;
  const short* Qp = QKV + ((size_t)b * SEQ) * 6144 + h * DK;
  const short* Kp = Qp + D_MODEL;
  const short* Vp = VT + ((size_t)bh * DK) * SEQ;   // [d][s]
  __shared__ __align__(16) short Ks[2][64 * 128];   // ^ (row&7)<<3 swizzle (shorts)
  __shared__ __align__(16) short Vs[2][128 * 64];
  __shared__ __align__(16) short Ps[8][16][72];

  const int krr = t >> 4, kcc = (t & 15) * 8;  // K stage: rows krr+32i, 16B cols
  const int vdd = t >> 3, vcc = (t & 7) * 8;   // V stage: d-rows vdd+64i
  const f32x4 z4 = {0.f, 0.f, 0.f, 0.f};

  for (int sub = 0; sub < 2; ++sub) {
    const int ts = sub ? (15 - a) : a;          // q-tile (128 rows) index
    const int nt = 2 * ts + 2;                  // KV tiles needed
    const int qrow0 = ts * 128 + w * 16;

    short8 qf[4];
    #pragma unroll
    for (int ki = 0; ki < 4; ++ki)
      qf[ki] = *(const short8*)(Qp + (size_t)(qrow0 + lr) * 6144 + ki * 32 + lg * 8);

    f32x4 acc[8];
    #pragma unroll
    for (int nd = 0; nd < 8; ++nd) acc[nd] = z4;
    float mrow[4], lsum[4];
    #pragma unroll
    for (int r = 0; r < 4; ++r) { mrow[r] = -INFINITY; lsum[r] = 0.f; }

    // prologue: stage KV tile 0 into buf 0
    uint4 krg[2], vrg[2];
    #pragma unroll
    for (int i = 0; i < 2; ++i) {
      krg[i] = *(const uint4*)(Kp + (size_t)(krr + 32 * i) * 6144 + kcc);
      vrg[i] = *(const uint4*)(Vp + (size_t)(vdd + 64 * i) * SEQ + vcc);
    }
    __syncthreads();   // prior subtile done reading LDS
    #pragma unroll
    for (int i = 0; i < 2; ++i) {
      int r = krr + 32 * i;
      *(uint4*)&Ks[0][(r * 128 + kcc) ^ ((r & 7) << 3)] = krg[i];
      int d = vdd + 64 * i;
      *(uint4*)&Vs[0][(d * 64 + vcc) ^ ((d & 7) << 3)] = vrg[i];
    }
    __syncthreads();

    int cur = 0;
    for (int tt = 0; tt < nt; ++tt) {
      const bool pre = (tt + 1 < nt);
      if (pre) {   // async: issue next tile's global loads before compute
        #pragma unroll
        for (int i = 0; i < 2; ++i) {
          krg[i] = *(const uint4*)(Kp + (size_t)((tt + 1) * 64 + krr + 32 * i) * 6144 + kcc);
          vrg[i] = *(const uint4*)(Vp + (size_t)(vdd + 64 * i) * SEQ + (tt + 1) * 64 + vcc);
        }
      }

      // S = Q K^T (16 q-rows x 64 kv)
      f32x4 sf[4] = {z4, z4, z4, z4};
      #pragma unroll
      for (int ki = 0; ki < 4; ++ki) {
        #pragma unroll
        for (int nk = 0; nk < 4; ++nk) {
          int rr = nk * 16 + lr;
          short8 kf = *(const short8*)&Ks[cur][(rr * 128 + ki * 32 + lg * 8) ^ ((rr & 7) << 3)];
          sf[nk] = __builtin_amdgcn_mfma_f32_16x16x32_bf16(qf[ki], kf, sf[nk], 0, 0, 0);
        }
      }

      const bool diag = (tt * 64 + 63 > qrow0);
      #pragma unroll
      for (int r = 0; r < 4; ++r) {
        int qg = qrow0 + lg * 4 + r;
        float s0 = sf[0][r] * SC, s1 = sf[1][r] * SC, s2 = sf[2][r] * SC, s3 = sf[3][r] * SC;
        if (diag) {
          int c0 = tt * 64 + lr;
          s0 = (c0      <= qg) ? s0 : -3.0e38f;
          s1 = (c0 + 16 <= qg) ? s1 : -3.0e38f;
          s2 = (c0 + 32 <= qg) ? s2 : -3.0e38f;
          s3 = (c0 + 48 <= qg) ? s3 : -3.0e38f;
        }
        float mx = fmaxf(fmaxf(s0, s1), fmaxf(s2, s3));
        mx = fmaxf(mx, __shfl_xor(mx, 1));
        mx = fmaxf(mx, __shfl_xor(mx, 2));
        mx = fmaxf(mx, __shfl_xor(mx, 4));
        mx = fmaxf(mx, __shfl_xor(mx, 8));
        float mnew = fmaxf(mrow[r], mx);
        float alpha = exp2f(mrow[r] - mnew);
        mrow[r] = mnew;
        float p0 = exp2f(s0 - mnew), p1 = exp2f(s1 - mnew),
              p2 = exp2f(s2 - mnew), p3 = exp2f(s3 - mnew);
        // deferred: per-lane partial row sum, reduced once in epilogue
        lsum[r] = lsum[r] * alpha + ((p0 + p1) + (p2 + p3));
        #pragma unroll
        for (int nd = 0; nd < 8; ++nd) acc[nd][r] *= alpha;
        short* pr = &Ps[w][lg * 4 + r][0];
        pr[lr]      = f2bf(p0);
        pr[16 + lr] = f2bf(p1);
        pr[32 + lr] = f2bf(p2);
        pr[48 + lr] = f2bf(p3);
      }
      asm volatile("s_waitcnt lgkmcnt(0)" ::: "memory");
      __builtin_amdgcn_sched_barrier(0);

      // O += P V
      short8 pf0 = *(const short8*)&Ps[w][lr][lg * 8];
      short8 pf1 = *(const short8*)&Ps[w][lr][32 + lg * 8];
      #pragma unroll
      for (int nd = 0; nd < 8; ++nd) {
        int rr = nd * 16 + lr;
        short8 vf0 = *(const short8*)&Vs[cur][(rr * 64 + lg * 8) ^ ((rr & 7) << 3)];
        short8 vf1 = *(const short8*)&Vs[cur][(rr * 64 + 32 + lg * 8) ^ ((rr & 7) << 3)];
        acc[nd] = __builtin_amdgcn_mfma_f32_16x16x32_bf16(pf0, vf0, acc[nd], 0, 0, 0);
        acc[nd] = __builtin_amdgcn_mfma_f32_16x16x32_bf16(pf1, vf1, acc[nd], 0, 0, 0);
      }
      __syncthreads();   // all waves done reading buf[cur]
      if (pre) {
        #pragma unroll
        for (int i = 0; i < 2; ++i) {
          int r = krr + 32 * i;
          *(uint4*)&Ks[cur ^ 1][(r * 128 + kcc) ^ ((r & 7) << 3)] = krg[i];
          int d = vdd + 64 * i;
          *(uint4*)&Vs[cur ^ 1][(d * 64 + vcc) ^ ((d & 7) << 3)] = vrg[i];
        }
      }
      __syncthreads();   // writes visible before next compute
      cur ^= 1;
    }

    // epilogue: reduce lsum across the 16-lane group, write O
    float inv[4];
    #pragma unroll
    for (int r = 0; r < 4; ++r) {
      float ls = lsum[r];
      ls += __shfl_xor(ls, 1);
      ls += __shfl_xor(ls, 2);
      ls += __shfl_xor(ls, 4);
      ls += __shfl_xor(ls, 8);
      inv[r] = 1.0f / ls;
    }
    #pragma unroll
    for (int nd = 0; nd < 8; ++nd)
      #pragma unroll
      for (int r = 0; r < 4; ++r) {
        int row = qrow0 + lg * 4 + r;
        O[(size_t)(b * SEQ + row) * D_MODEL + h * DK + nd * 16 + lr] = f2bf(acc[nd][r] * inv[r]);
      }
  }
}

// ======== FALLBACK PATH (round-2 verified kernels) ========
template<int EPI>
__global__ __launch_bounds__(256) void gemm_bt(const short* __restrict__ A,
                                               const float* __restrict__ B,
                                               void* Cv,
                                               const float* resid,
                                               int M, int N, int K) {
  __shared__ __align__(16) short As[128][72];
  __shared__ __align__(16) short Bs[128][72];
  const int t = threadIdx.x;
  const int m0 = blockIdx.x * 128, n0 = blockIdx.y * 128;
  const int wave = t >> 6, lane = t & 63, lr = lane & 15, lg = lane >> 4;
  const int wr = (wave >> 1) * 64, wc = (wave & 1) * 64;

  f32x4 acc[4][4];
  const f32x4 z4 = {0.f, 0.f, 0.f, 0.f};
  #pragma unroll
  for (int m = 0; m < 4; ++m)
    #pragma unroll
    for (int n = 0; n < 4; ++n) acc[m][n] = z4;

  int ar[4], ac[4];
  #pragma unroll
  for (int i = 0; i < 4; ++i) { int u = t + 256*i; ar[i] = u >> 3; ac[i] = (u & 7) * 8; }

  for (int k0 = 0; k0 < K; k0 += 64) {
    #pragma unroll
    for (int i = 0; i < 4; ++i) {
      uint4 va = *(const uint4*)(A + (size_t)(m0 + ar[i]) * K + k0 + ac[i]);
      *(uint4*)&As[ar[i]][ac[i]] = va;
    }
    #pragma unroll
    for (int i = 0; i < 4; ++i) {
      const float4* bp = (const float4*)(B + (size_t)(n0 + ar[i]) * K + k0 + ac[i]);
      float4 b0 = bp[0], b1 = bp[1];
      short8 pb = { f2bf(b0.x), f2bf(b0.y), f2bf(b0.z), f2bf(b0.w),
                    f2bf(b1.x), f2bf(b1.y), f2bf(b1.z), f2bf(b1.w) };
      *(short8*)&Bs[ar[i]][ac[i]] = pb;
    }
    __syncthreads();
    #pragma unroll
    for (int kk = 0; kk < 64; kk += 32) {
      short8 af[4], bfr[4];
      #pragma unroll
      for (int m = 0; m < 4; ++m) af[m]  = *(const short8*)&As[wr + m*16 + lr][kk + lg*8];
      #pragma unroll
      for (int n = 0; n < 4; ++n) bfr[n] = *(const short8*)&Bs[wc + n*16 + lr][kk + lg*8];
      #pragma unroll
      for (int m = 0; m < 4; ++m)
        #pragma unroll
        for (int n = 0; n < 4; ++n)
          acc[m][n] = __builtin_amdgcn_mfma_f32_16x16x32_bf16(af[m], bfr[n], acc[m][n], 0, 0, 0);
    }
    __syncthreads();
  }

  #pragma unroll
  for (int m = 0; m < 4; ++m)
    #pragma unroll
    for (int n = 0; n < 4; ++n)
      #pragma unroll
      for (int r = 0; r < 4; ++r) {
        int row = m0 + wr + m*16 + lg*4 + r;
        int col = n0 + wc + n*16 + lr;
        size_t idx = (size_t)row * N + col;
        float vv = acc[m][n][r];
        if (EPI == 0) {
          ((short*)Cv)[idx] = f2bf(vv);
        } else if (EPI == 1) {
          float gl = 0.5f * vv * (1.0f + erff(vv * 0.70710678118654752f));
          ((short*)Cv)[idx] = f2bf(gl);
        } else {
          ((float*)Cv)[idx] = vv + resid[idx];
        }
      }
}

__global__ __launch_bounds__(256) void attn_k(const short* __restrict__ Q,
                                              const short* __restrict__ K,
                                              const short* __restrict__ V,
                                              short* __restrict__ O) {
  const float scale = 0.08838834764831845f;
  const int qt = blockIdx.x;
  const int bh = blockIdx.y;
  const int b = bh >> 4, h = bh & 15;
  const size_t base = ((size_t)b * SEQ) * D_MODEL + (size_t)h * DK;
  const int t = threadIdx.x, wave = t >> 6, lane = t & 63, lr = lane & 15, lg = lane >> 4;

  __shared__ __align__(16) short Ks[32][136];
  __shared__ __align__(16) short Vt[128][40];
  __shared__ __align__(16) short Ps[4][32][40];

  const int qrow0 = qt * 128 + wave * 32;
  short8 qf[2][4];
  #pragma unroll
  for (int mq = 0; mq < 2; ++mq)
    #pragma unroll
    for (int ki = 0; ki < 4; ++ki)
      qf[mq][ki] = *(const short8*)(Q + base + (size_t)(qrow0 + mq*16 + lr) * D_MODEL + ki*32 + lg*8);

  f32x4 acc[2][8];
  const f32x4 z4 = {0.f, 0.f, 0.f, 0.f};
  #pragma unroll
  for (int mq = 0; mq < 2; ++mq)
    #pragma unroll
    for (int nd = 0; nd < 8; ++nd) acc[mq][nd] = z4;
  float mrow[2][4], lsum[2][4];
  #pragma unroll
  for (int mq = 0; mq < 2; ++mq)
    #pragma unroll
    for (int r = 0; r < 4; ++r) { mrow[mq][r] = -INFINITY; lsum[mq][r] = 0.f; }

  const int lastt = qt * 4 + 3;
  for (int tt = 0; tt <= lastt; ++tt) {
    #pragma unroll
    for (int i = 0; i < 2; ++i) {
      int u = t + 256*i; int r = u >> 4; int c = (u & 15) * 8;
      *(uint4*)&Ks[r][c] = *(const uint4*)(K + base + (size_t)(tt*32 + r) * D_MODEL + c);
      uint4 vv = *(const uint4*)(V + base + (size_t)(tt*32 + r) * D_MODEL + c);
      const short* sv = (const short*)&vv;
      #pragma unroll
      for (int j = 0; j < 8; ++j) Vt[c + j][r] = sv[j];
    }
    __syncthreads();
    if (tt <= qt * 4 + wave) {
      f32x4 sf[2][2] = {{z4, z4}, {z4, z4}};
      #pragma unroll
      for (int ki = 0; ki < 4; ++ki) {
        short8 kf0 = *(const short8*)&Ks[lr][ki*32 + lg*8];
        short8 kf1 = *(const short8*)&Ks[16 + lr][ki*32 + lg*8];
        sf[0][0] = __builtin_amdgcn_mfma_f32_16x16x32_bf16(qf[0][ki], kf0, sf[0][0], 0, 0, 0);
        sf[0][1] = __builtin_amdgcn_mfma_f32_16x16x32_bf16(qf[0][ki], kf1, sf[0][1], 0, 0, 0);
        sf[1][0] = __builtin_amdgcn_mfma_f32_16x16x32_bf16(qf[1][ki], kf0, sf[1][0], 0, 0, 0);
        sf[1][1] = __builtin_amdgcn_mfma_f32_16x16x32_bf16(qf[1][ki], kf1, sf[1][1], 0, 0, 0);
      }
      #pragma unroll
      for (int mq = 0; mq < 2; ++mq) {
        #pragma unroll
        for (int r = 0; r < 4; ++r) {
          int qg = qrow0 + mq*16 + lg*4 + r;
          float s0 = sf[mq][0][r] * scale;
          float s1 = sf[mq][1][r] * scale;
          if (tt*32 + lr > qg)       s0 = -INFINITY;
          if (tt*32 + 16 + lr > qg)  s1 = -INFINITY;
          float mx = fmaxf(s0, s1);
          mx = fmaxf(mx, __shfl_xor(mx, 1));
          mx = fmaxf(mx, __shfl_xor(mx, 2));
          mx = fmaxf(mx, __shfl_xor(mx, 4));
          mx = fmaxf(mx, __shfl_xor(mx, 8));
          float mnew = fmaxf(mrow[mq][r], mx);
          float alpha = __expf(mrow[mq][r] - mnew);
          mrow[mq][r] = mnew;
          float p0 = __expf(s0 - mnew);
          float p1 = __expf(s1 - mnew);
          float ps = p0 + p1;
          ps += __shfl_xor(ps, 1);
          ps += __shfl_xor(ps, 2);
          ps += __shfl_xor(ps, 4);
          ps += __shfl_xor(ps, 8);
          lsum[mq][r] = lsum[mq][r] * alpha + ps;
          #pragma unroll
          for (int nd = 0; nd < 8; ++nd) acc[mq][nd][r] *= alpha;
          Ps[wave][mq*16 + lg*4 + r][lr]      = f2bf(p0);
          Ps[wave][mq*16 + lg*4 + r][16 + lr] = f2bf(p1);
        }
      }
      asm volatile("s_waitcnt lgkmcnt(0)" ::: "memory");
      short8 pf0 = *(const short8*)&Ps[wave][lr][lg*8];
      short8 pf1 = *(const short8*)&Ps[wave][16 + lr][lg*8];
      #pragma unroll
      for (int nd = 0; nd < 8; ++nd) {
        short8 vf = *(const short8*)&Vt[nd*16 + lr][lg*8];
        acc[0][nd] = __builtin_amdgcn_mfma_f32_16x16x32_bf16(pf0, vf, acc[0][nd], 0, 0, 0);
        acc[1][nd] = __builtin_amdgcn_mfma_f32_16x16x32_bf16(pf1, vf, acc[1][nd], 0, 0, 0);
      }
    }
    __syncthreads();
  }

  #pragma unroll
  for (int mq = 0; mq < 2; ++mq)
    #pragma unroll
    for (int nd = 0; nd < 8; ++nd)
      #pragma unroll
      for (int r = 0; r < 4; ++r) {
        int row = qrow0 + mq*16 + lg*4 + r;
        O[base + (size_t)row * D_MODEL + nd*16 + lr] = f2bf(acc[mq][nd][r] / lsum[mq][r]);
      }
}

// ---------------- launch ----------------
extern "C" void kernel_launch(void* const* d_in, const int* in_sizes, int n_in,
                              void* d_out, int out_size, void* d_ws, size_t ws_size,
                              hipStream_t stream) {
  const float* x  = (const float*)d_in[0];
  const float* wq = (const float*)d_in[1];
  const float* wk = (const float*)d_in[2];
  const float* wv = (const float*)d_in[3];
  const float* wo = (const float*)d_in[4];
  const float* w1 = (const float*)d_in[5];
  const float* w2 = (const float*)d_in[6];
  const float* g1 = (const float*)d_in[7];
  const float* g2 = (const float*)d_in[8];
  float* out = (float*)d_out;
  char* ws = (char*)d_ws;

  const size_t NEED = (size_t)192 << 20;
  if (ws_size >= NEED) {
    // fast path layout (192 MiB):
    //   [0,24M)    wqkv bf16 [6144][2048]
    //   [24,32M)   wo bf16
    //   [32,64M)   w1 bf16
    //   [64,96M)   w2 bf16
    //   [96,144M)  qkv bf16 [4096][6144]   (dead after attn; hb overlaps)
    //   [144,160M) vt bf16 [32][128][2048] (dead after attn)
    //   [160,176M) attn-out bf16
    //   [176,192M) xn bf16
    //   [96,160M)  hb bf16 [4096][8192]    (FFN phase)
    short* wqkv = (short*)(ws);
    short* wo_b = (short*)(ws + ((size_t)24 << 20));
    short* w1_b = (short*)(ws + ((size_t)32 << 20));
    short* w2_b = (short*)(ws + ((size_t)64 << 20));
    short* qkv  = (short*)(ws + ((size_t)96 << 20));
    short* vt   = (short*)(ws + ((size_t)144 << 20));
    short* ab   = (short*)(ws + ((size_t)160 << 20));
    short* xn   = (short*)(ws + ((size_t)176 << 20));
    short* hb   = (short*)(ws + ((size_t)96 << 20));

    const int NW = D_MODEL * D_MODEL / 8;
    f2b_k<<<(NW + 255) / 256, 256, 0, stream>>>(wq, wqkv,                   NW);
    f2b_k<<<(NW + 255) / 256, 256, 0, stream>>>(wk, wqkv + (size_t)D_MODEL * D_MODEL,     NW);
    f2b_k<<<(NW + 255) / 256, 256, 0, stream>>>(wv, wqkv + (size_t)2 * D_MODEL * D_MODEL, NW);
    f2b_k<<<(NW + 255) / 256, 256, 0, stream>>>(wo, wo_b, NW);
    const int NF = DFF * D_MODEL / 8;
    f2b_k<<<(NF + 255) / 256, 256, 0, stream>>>(w1, w1_b, NF);
    f2b_k<<<(NF + 255) / 256, 256, 0, stream>>>(w2, w2_b, NF);

    rmsnorm_k<<<MROWS, 256, 0, stream>>>(x, g1, xn);
    gemm_fast<0><<<dim3(MROWS/128, 6144/128), 256, 0, stream>>>(xn, wqkv, qkv, nullptr, MROWS, 6144, D_MODEL);
    vtrans<<<dim3(SEQ/64, BATCH*NHEAD), 256, 0, stream>>>(qkv, vt);
    attn3<<<dim3(8, BATCH*NHEAD), 512, 0, stream>>>(qkv, vt, ab);
    gemm_fast<2><<<dim3(MROWS/128, D_MODEL/128), 256, 0, stream>>>(ab, wo_b, out, x, MROWS, D_MODEL, D_MODEL);
    rmsnorm_k<<<MROWS, 256, 0, stream>>>(out, g2, xn);
    gemm_fast<1><<<dim3(MROWS/128, DFF/128), 256, 0, stream>>>(xn, w1_b, hb, nullptr, MROWS, DFF, D_MODEL);
    gemm_fast<2><<<dim3(MROWS/128, D_MODEL/128), 256, 0, stream>>>(hb, w2_b, out, out, MROWS, D_MODEL, DFF);
  } else {
    // fallback: round-2 verified path (80 MiB)
    short* qb = (short*)(ws + ((size_t)0  << 20));
    short* kb = (short*)(ws + ((size_t)16 << 20));
    short* vb = (short*)(ws + ((size_t)32 << 20));
    short* ab = (short*)(ws + ((size_t)48 << 20));
    short* xn = (short*)(ws + ((size_t)64 << 20));
    short* hb = (short*)(ws + ((size_t)0  << 20));

    dim3 gproj(MROWS / 128, D_MODEL / 128);
    rmsnorm_k<<<MROWS, 256, 0, stream>>>(x, g1, xn);
    gemm_bt<0><<<gproj, 256, 0, stream>>>(xn, wq, qb, nullptr, MROWS, D_MODEL, D_MODEL);
    gemm_bt<0><<<gproj, 256, 0, stream>>>(xn, wk, kb, nullptr, MROWS, D_MODEL, D_MODEL);
    gemm_bt<0><<<gproj, 256, 0, stream>>>(xn, wv, vb, nullptr, MROWS, D_MODEL, D_MODEL);
    attn_k<<<dim3(SEQ / 128, BATCH * NHEAD), 256, 0, stream>>>(qb, kb, vb, ab);
    gemm_bt<2><<<gproj, 256, 0, stream>>>(ab, wo, out, x, MROWS, D_MODEL, D_MODEL);
    rmsnorm_k<<<MROWS, 256, 0, stream>>>(out, g2, xn);
    for (int half = 0; half < 2; ++half) {
      const short* xh = xn  + (size_t)half * 2048 * D_MODEL;
      float*       oh = out + (size_t)half * 2048 * D_MODEL;
      gemm_bt<1><<<dim3(2048 / 128, DFF / 128), 256, 0, stream>>>(xh, w1, hb, nullptr, 2048, DFF, D_MODEL);
      gemm_bt<2><<<dim3(2048 / 128, D_MODEL / 128), 256, 0, stream>>>(hb, w2, oh, oh, 2048, D_MODEL, DFF);
    }
  }
}

// Round 5
// 794.068 us; speedup vs baseline: 1.6026x; 1.1549x over previous
//
#include <hip/hip_runtime.h>
#include <hip/hip_bf16.h>
#include <math.h>

// ---- problem constants ----
#define D_MODEL 2048
#define SEQ     2048
#define BATCH   2
#define NHEAD   16
#define DK      128
#define DFF     8192
#define MROWS   (BATCH*SEQ)   // 4096 rows

typedef short short8 __attribute__((ext_vector_type(8)));   // 8 bf16 in 4 VGPRs
typedef float f32x4  __attribute__((ext_vector_type(4)));

__device__ __forceinline__ short f2bf(float f) {
  union { __hip_bfloat16 b; short s; } u;
  u.b = __float2bfloat16(f);
  return u.s;
}

__device__ __forceinline__ void gload_lds16(const void* g, void* l) {
  __builtin_amdgcn_global_load_lds(
      (const __attribute__((address_space(1))) unsigned int*)g,
      (__attribute__((address_space(3))) unsigned int*)l, 16, 0, 0);
}

#define MF(a, b, c) __builtin_amdgcn_mfma_f32_16x16x32_bf16(a, b, c, 0, 0, 0)

// ---------------- RMSNorm: fp32 in -> bf16 out ----------------
__global__ __launch_bounds__(256) void rmsnorm_k(const float* __restrict__ x,
                                                 const float* __restrict__ g,
                                                 short* __restrict__ o) {
  const int row = blockIdx.x;
  const int t = threadIdx.x;
  const float4* xr = (const float4*)(x + (size_t)row * D_MODEL);
  const float4* gr = (const float4*)g;
  float4 v0 = xr[2*t], v1 = xr[2*t+1];
  float s = v0.x*v0.x + v0.y*v0.y + v0.z*v0.z + v0.w*v0.w
          + v1.x*v1.x + v1.y*v1.y + v1.z*v1.z + v1.w*v1.w;
  #pragma unroll
  for (int off = 1; off < 64; off <<= 1) s += __shfl_xor(s, off);
  __shared__ float red[4];
  if ((t & 63) == 0) red[t >> 6] = s;
  __syncthreads();
  float tot = red[0] + red[1] + red[2] + red[3];
  float inv = rsqrtf(tot * (1.0f / D_MODEL) + 1e-5f);
  float4 g0 = gr[2*t], g1v = gr[2*t+1];
  short8 ov;
  ov[0] = f2bf(v0.x * inv * g0.x);
  ov[1] = f2bf(v0.y * inv * g0.y);
  ov[2] = f2bf(v0.z * inv * g0.z);
  ov[3] = f2bf(v0.w * inv * g0.w);
  ov[4] = f2bf(v1.x * inv * g1v.x);
  ov[5] = f2bf(v1.y * inv * g1v.y);
  ov[6] = f2bf(v1.z * inv * g1v.z);
  ov[7] = f2bf(v1.w * inv * g1v.w);
  *((short8*)(o + (size_t)row * D_MODEL) + t) = ov;
}

// ---------------- fp32 -> bf16 convert (weights, one-time) ----------------
__global__ __launch_bounds__(256) void f2b_k(const float* __restrict__ src,
                                             short* __restrict__ dst, int n8) {
  int i = blockIdx.x * 256 + threadIdx.x;
  if (i >= n8) return;
  const float4* s4 = (const float4*)src + 2 * (size_t)i;
  float4 a = s4[0], b = s4[1];
  short8 o = { f2bf(a.x), f2bf(a.y), f2bf(a.z), f2bf(a.w),
               f2bf(b.x), f2bf(b.y), f2bf(b.z), f2bf(b.w) };
  *((short8*)dst + i) = o;
}

// ======== Phase-pipelined GEMM: C[M,N] = A[M,K](bf16) * B[N,K](bf16)^T ========
// BM=128, BN=256, BK=64, 512 threads (8 waves as 2Mx4N, 64x64 each).
// Counted-vmcnt deep pipeline: A(t+1) staged one tile ahead (vmcnt(2) boundary),
// B(t+1) staged during tile t, A(t+2) staged into the CURRENT buffer after all
// A-reads have landed in registers (per-phase barrier+lgkmcnt protocol).
// LDS XOR-swizzle (row&7)<<3 shorts, applied via pre-swizzled global source
// (linear gload_lds dest) + swizzled ds_read.  EPI: 0 bf16; 1 GELU bf16; 2 +resid fp32.
template<int EPI>
__global__ __launch_bounds__(512, 2) void gemm8p(const short* __restrict__ A,
                                                 const short* __restrict__ B,
                                                 void* Cv,
                                                 const float* __restrict__ resid,
                                                 int M, int N, int K, int nbx) {
  __shared__ __align__(16) short As[2][128 * 64];   // 32 KB
  __shared__ __align__(16) short Bs[2][256 * 64];   // 64 KB
  const int nk = K >> 6;
  const int cpx = gridDim.x >> 3;                   // nwg % 8 == 0 (bijective XCD swizzle)
  const int lin = (blockIdx.x & 7) * cpx + (blockIdx.x >> 3);
  const int bx = lin % nbx, by = lin / nbx;         // bx fast -> same-XCD blocks share B panel
  const int m0 = bx * 128, n0 = by * 256;
  const int t = threadIdx.x, w = t >> 6, lane = t & 63, lr = lane & 15, lg = lane >> 4;
  const int wrA = (w >> 2) * 64, wcB = (w & 3) * 64;
  const unsigned aBase = (unsigned)(size_t)(const __attribute__((address_space(3))) short*)&As[0][0];
  const unsigned bBase = (unsigned)(size_t)(const __attribute__((address_space(3))) short*)&Bs[0][0];

  // asm staging: wave-uniform LDS base in m0, per-lane global addr, 16B/lane
#define STG(gptr, ldsbyte) { \
    unsigned _m0v = (unsigned)__builtin_amdgcn_readfirstlane((int)(ldsbyte)); \
    asm volatile("s_mov_b32 m0, %1\n\tglobal_load_lds_dwordx4 %0, off" \
                 :: "v"(gptr), "s"(_m0v) : "memory"); }
  // A-half h (64 rows) of K-tile tt into parity pb: 1 chunk (16B) / thread
#define STAGE_A(h, tt, pb) { \
    int rl_ = t >> 3, cc_ = t & 7; \
    const short* g_ = A + (size_t)(m0 + (h)*64 + rl_) * K + (tt)*64 + ((cc_ ^ (rl_ & 7)) << 3); \
    STG(g_, aBase + (unsigned)(pb)*16384u + (unsigned)(h)*8192u + (unsigned)(w * 1024)); }
  // B-half h (128 rows) of K-tile tt into parity pb: 2 chunks / thread
#define STAGE_B(h, tt, pb) { \
    { int ci_ = t;       int rl_ = ci_ >> 3, cc_ = ci_ & 7; \
      const short* g_ = B + (size_t)(n0 + (h)*128 + rl_) * K + (tt)*64 + ((cc_ ^ (rl_ & 7)) << 3); \
      STG(g_, bBase + (unsigned)(pb)*32768u + (unsigned)(h)*16384u + (unsigned)(w * 1024)); } \
    { int ci_ = t + 512; int rl_ = ci_ >> 3, cc_ = ci_ & 7; \
      const short* g_ = B + (size_t)(n0 + (h)*128 + rl_) * K + (tt)*64 + ((cc_ ^ (rl_ & 7)) << 3); \
      STG(g_, bBase + (unsigned)(pb)*32768u + (unsigned)(h)*16384u + (unsigned)(w * 1024 + 8192)); } }
#define RDA(dst, m_, kk_, p_) { int rr_ = wrA + (m_)*16 + lr; \
    dst = *(const short8*)&As[p_][rr_ * 64 + (((kk_)*32 + lg*8) ^ ((rr_ & 7) << 3))]; }
#define RDB(dst, n_, kk_, p_) { int rr_ = wcB + (n_)*16 + lr; \
    dst = *(const short8*)&Bs[p_][rr_ * 64 + (((kk_)*32 + lg*8) ^ ((rr_ & 7) << 3))]; }

  f32x4 acc[4][4];
  const f32x4 z4 = {0.f, 0.f, 0.f, 0.f};
  #pragma unroll
  for (int m = 0; m < 4; ++m)
    #pragma unroll
    for (int n = 0; n < 4; ++n) acc[m][n] = z4;

  // prologue: tile 0 fully + A-halves of tile 1 (stay in flight across boundary 0)
  STAGE_A(0, 0, 0); STAGE_A(1, 0, 0);
  STAGE_B(0, 0, 0); STAGE_B(1, 0, 0);
  STAGE_A(0, 1, 1); STAGE_A(1, 1, 1);

  for (int tt = 0; tt < nk; ++tt) {
    const int p = tt & 1;
    // ---- tile boundary: tile tt fully landed; A(tt+1) (2 loads) stays in flight ----
    if (tt + 1 < nk) { asm volatile("s_waitcnt vmcnt(2)" ::: "memory"); }
    else             { asm volatile("s_waitcnt vmcnt(0)" ::: "memory"); }
    __builtin_amdgcn_s_barrier();
    asm volatile("" ::: "memory");

    // ---- phase 0: stage B0(tt+1); read all A-frags + B-frags n0-1; MFMA n0-1 ----
    if (tt + 1 < nk) STAGE_B(0, tt + 1, p ^ 1);
    short8 a0[4][2], b0[2][2];
    #pragma unroll
    for (int m = 0; m < 4; ++m) { RDA(a0[m][0], m, 0, p); RDA(a0[m][1], m, 1, p); }
    #pragma unroll
    for (int n = 0; n < 2; ++n) { RDB(b0[n][0], n, 0, p); RDB(b0[n][1], n, 1, p); }
    asm volatile("" ::: "memory");
    __builtin_amdgcn_s_barrier();
    asm volatile("s_waitcnt lgkmcnt(0)" ::: "memory");
    __builtin_amdgcn_sched_barrier(0);
    __builtin_amdgcn_s_setprio(1);
    #pragma unroll
    for (int m = 0; m < 4; ++m)
      #pragma unroll
      for (int n = 0; n < 2; ++n) {
        acc[m][n] = MF(a0[m][0], b0[n][0], acc[m][n]);
        acc[m][n] = MF(a0[m][1], b0[n][1], acc[m][n]);
      }
    __builtin_amdgcn_s_setprio(0);
    asm volatile("" ::: "memory");
    __builtin_amdgcn_s_barrier();   // all waves' ds_reads complete before A-overwrite below

    // ---- phase 1: stage B1(tt+1) + A(tt+2) (overwrites As[p] - reads done); MFMA n2-3 ----
    if (tt + 1 < nk) STAGE_B(1, tt + 1, p ^ 1);
    if (tt + 2 < nk) { STAGE_A(0, tt + 2, p); STAGE_A(1, tt + 2, p); }
    short8 b1[2][2];
    #pragma unroll
    for (int n = 0; n < 2; ++n) { RDB(b1[n][0], n + 2, 0, p); RDB(b1[n][1], n + 2, 1, p); }
    asm volatile("" ::: "memory");
    __builtin_amdgcn_s_barrier();
    asm volatile("s_waitcnt lgkmcnt(0)" ::: "memory");
    __builtin_amdgcn_sched_barrier(0);
    __builtin_amdgcn_s_setprio(1);
    #pragma unroll
    for (int m = 0; m < 4; ++m)
      #pragma unroll
      for (int n = 0; n < 2; ++n) {
        acc[m][n + 2] = MF(a0[m][0], b1[n][0], acc[m][n + 2]);
        acc[m][n + 2] = MF(a0[m][1], b1[n][1], acc[m][n + 2]);
      }
    __builtin_amdgcn_s_setprio(0);
    asm volatile("" ::: "memory");
    // (no phase-1 end barrier: next boundary's barrier covers the b1-read protocol)
  }

  // ---- epilogue ----
  #pragma unroll
  for (int m = 0; m < 4; ++m)
    #pragma unroll
    for (int n = 0; n < 4; ++n)
      #pragma unroll
      for (int r = 0; r < 4; ++r) {
        int row = m0 + wrA + m * 16 + lg * 4 + r;
        int col = n0 + wcB + n * 16 + lr;
        size_t idx = (size_t)row * N + col;
        float vv = acc[m][n][r];
        if (EPI == 0) {
          ((short*)Cv)[idx] = f2bf(vv);
        } else if (EPI == 1) {
          float gl = 0.5f * vv * (1.0f + erff(vv * 0.70710678118654752f));
          ((short*)Cv)[idx] = f2bf(gl);
        } else {
          ((float*)Cv)[idx] = vv + resid[idx];
        }
      }
#undef STG
#undef STAGE_A
#undef STAGE_B
#undef RDA
#undef RDB
}

// ---------------- V transpose: qkv[.., v cols] -> vt[b][h][d][s] ----------------
__global__ __launch_bounds__(256) void vtrans(const short* __restrict__ QKV,
                                              short* __restrict__ VT) {
  const int st = blockIdx.x;   // s tile of 64
  const int bh = blockIdx.y;
  const int b = bh >> 4, h = bh & 15;
  const int t = threadIdx.x;
  __shared__ __align__(16) short T[64 * 128];
  const short* Vsrc = QKV + ((size_t)b * SEQ) * 6144 + 2 * D_MODEL + h * DK;
  {
    int r = t >> 4, c = (t & 15) * 8;
    #pragma unroll
    for (int i = 0; i < 4; ++i) {
      int rr = r + 16 * i;
      uint4 vv = *(const uint4*)(Vsrc + (size_t)(st * 64 + rr) * 6144 + c);
      *(uint4*)&T[rr * 128 + (c ^ (((rr >> 3) & 7) << 3))] = vv;
    }
  }
  __syncthreads();
  short* dst = VT + ((size_t)bh * DK) * SEQ + st * 64;
  {
    int c2 = (t & 7) * 8;
    #pragma unroll
    for (int i = 0; i < 4; ++i) {
      int d = (t >> 3) + 32 * i;
      short8 ov;
      #pragma unroll
      for (int j = 0; j < 8; ++j)
        ov[j] = T[(c2 + j) * 128 + (d ^ ((((c2 + j) >> 3) & 7) << 3))];
      *(short8*)(dst + (size_t)d * SEQ + c2) = ov;
    }
  }
}

// ---------------- Flash attention v3 (round-4 verified) ----------------
__global__ __launch_bounds__(512, 2) void attn3(const short* __restrict__ QKV,
                                                const short* __restrict__ VT,
                                                short* __restrict__ O) {
  const float SC = 0.12751743f;   // (1/sqrt(128)) * log2(e)
  const int a = blockIdx.x, bh = blockIdx.y;
  const int b = bh >> 4, h = bh & 15;
  const int t = threadIdx.x, w = t >> 6, lane = t & 63, lr = lane & 15, lg = lane >> 4;
  const short* Qp = QKV + ((size_t)b * SEQ) * 6144 + h * DK;
  const short* Kp = Qp + D_MODEL;
  const short* Vp = VT + ((size_t)bh * DK) * SEQ;   // [d][s]
  __shared__ __align__(16) short Ks[2][64 * 128];
  __shared__ __align__(16) short Vs[2][128 * 64];
  __shared__ __align__(16) short Ps[8][16][72];

  const int krr = t >> 4, kcc = (t & 15) * 8;
  const int vdd = t >> 3, vcc = (t & 7) * 8;
  const f32x4 z4 = {0.f, 0.f, 0.f, 0.f};

  for (int sub = 0; sub < 2; ++sub) {
    const int ts = sub ? (15 - a) : a;
    const int nt = 2 * ts + 2;
    const int qrow0 = ts * 128 + w * 16;

    short8 qf[4];
    #pragma unroll
    for (int ki = 0; ki < 4; ++ki)
      qf[ki] = *(const short8*)(Qp + (size_t)(qrow0 + lr) * 6144 + ki * 32 + lg * 8);

    f32x4 acc[8];
    #pragma unroll
    for (int nd = 0; nd < 8; ++nd) acc[nd] = z4;
    float mrow[4], lsum[4];
    #pragma unroll
    for (int r = 0; r < 4; ++r) { mrow[r] = -INFINITY; lsum[r] = 0.f; }

    uint4 krg[2], vrg[2];
    #pragma unroll
    for (int i = 0; i < 2; ++i) {
      krg[i] = *(const uint4*)(Kp + (size_t)(krr + 32 * i) * 6144 + kcc);
      vrg[i] = *(const uint4*)(Vp + (size_t)(vdd + 64 * i) * SEQ + vcc);
    }
    __syncthreads();
    #pragma unroll
    for (int i = 0; i < 2; ++i) {
      int r = krr + 32 * i;
      *(uint4*)&Ks[0][(r * 128 + kcc) ^ ((r & 7) << 3)] = krg[i];
      int d = vdd + 64 * i;
      *(uint4*)&Vs[0][(d * 64 + vcc) ^ ((d & 7) << 3)] = vrg[i];
    }
    __syncthreads();

    int cur = 0;
    for (int tt = 0; tt < nt; ++tt) {
      const bool pre = (tt + 1 < nt);
      if (pre) {
        #pragma unroll
        for (int i = 0; i < 2; ++i) {
          krg[i] = *(const uint4*)(Kp + (size_t)((tt + 1) * 64 + krr + 32 * i) * 6144 + kcc);
          vrg[i] = *(const uint4*)(Vp + (size_t)(vdd + 64 * i) * SEQ + (tt + 1) * 64 + vcc);
        }
      }

      f32x4 sf[4] = {z4, z4, z4, z4};
      #pragma unroll
      for (int ki = 0; ki < 4; ++ki) {
        #pragma unroll
        for (int nk = 0; nk < 4; ++nk) {
          int rr = nk * 16 + lr;
          short8 kf = *(const short8*)&Ks[cur][(rr * 128 + ki * 32 + lg * 8) ^ ((rr & 7) << 3)];
          sf[nk] = MF(qf[ki], kf, sf[nk]);
        }
      }

      const bool diag = (tt * 64 + 63 > qrow0);
      #pragma unroll
      for (int r = 0; r < 4; ++r) {
        int qg = qrow0 + lg * 4 + r;
        float s0 = sf[0][r] * SC, s1 = sf[1][r] * SC, s2 = sf[2][r] * SC, s3 = sf[3][r] * SC;
        if (diag) {
          int c0 = tt * 64 + lr;
          s0 = (c0      <= qg) ? s0 : -3.0e38f;
          s1 = (c0 + 16 <= qg) ? s1 : -3.0e38f;
          s2 = (c0 + 32 <= qg) ? s2 : -3.0e38f;
          s3 = (c0 + 48 <= qg) ? s3 : -3.0e38f;
        }
        float mx = fmaxf(fmaxf(s0, s1), fmaxf(s2, s3));
        mx = fmaxf(mx, __shfl_xor(mx, 1));
        mx = fmaxf(mx, __shfl_xor(mx, 2));
        mx = fmaxf(mx, __shfl_xor(mx, 4));
        mx = fmaxf(mx, __shfl_xor(mx, 8));
        float mnew = fmaxf(mrow[r], mx);
        float alpha = exp2f(mrow[r] - mnew);
        mrow[r] = mnew;
        float p0 = exp2f(s0 - mnew), p1 = exp2f(s1 - mnew),
              p2 = exp2f(s2 - mnew), p3 = exp2f(s3 - mnew);
        lsum[r] = lsum[r] * alpha + ((p0 + p1) + (p2 + p3));
        #pragma unroll
        for (int nd = 0; nd < 8; ++nd) acc[nd][r] *= alpha;
        short* pr = &Ps[w][lg * 4 + r][0];
        pr[lr]      = f2bf(p0);
        pr[16 + lr] = f2bf(p1);
        pr[32 + lr] = f2bf(p2);
        pr[48 + lr] = f2bf(p3);
      }
      asm volatile("s_waitcnt lgkmcnt(0)" ::: "memory");
      __builtin_amdgcn_sched_barrier(0);

      short8 pf0 = *(const short8*)&Ps[w][lr][lg * 8];
      short8 pf1 = *(const short8*)&Ps[w][lr][32 + lg * 8];
      #pragma unroll
      for (int nd = 0; nd < 8; ++nd) {
        int rr = nd * 16 + lr;
        short8 vf0 = *(const short8*)&Vs[cur][(rr * 64 + lg * 8) ^ ((rr & 7) << 3)];
        short8 vf1 = *(const short8*)&Vs[cur][(rr * 64 + 32 + lg * 8) ^ ((rr & 7) << 3)];
        acc[nd] = MF(pf0, vf0, acc[nd]);
        acc[nd] = MF(pf1, vf1, acc[nd]);
      }
      __syncthreads();
      if (pre) {
        #pragma unroll
        for (int i = 0; i < 2; ++i) {
          int r = krr + 32 * i;
          *(uint4*)&Ks[cur ^ 1][(r * 128 + kcc) ^ ((r & 7) << 3)] = krg[i];
          int d = vdd + 64 * i;
          *(uint4*)&Vs[cur ^ 1][(d * 64 + vcc) ^ ((d & 7) << 3)] = vrg[i];
        }
      }
      __syncthreads();
      cur ^= 1;
    }

    float inv[4];
    #pragma unroll
    for (int r = 0; r < 4; ++r) {
      float ls = lsum[r];
      ls += __shfl_xor(ls, 1);
      ls += __shfl_xor(ls, 2);
      ls += __shfl_xor(ls, 4);
      ls += __shfl_xor(ls, 8);
      inv[r] = 1.0f / ls;
    }
    #pragma unroll
    for (int nd = 0; nd < 8; ++nd)
      #pragma unroll
      for (int r = 0; r < 4; ++r) {
        int row = qrow0 + lg * 4 + r;
        O[(size_t)(b * SEQ + row) * D_MODEL + h * DK + nd * 16 + lr] = f2bf(acc[nd][r] * inv[r]);
      }
  }
}

// ======== FALLBACK PATH (round-2 verified kernels) ========
template<int EPI>
__global__ __launch_bounds__(256) void gemm_bt(const short* __restrict__ A,
                                               const float* __restrict__ B,
                                               void* Cv,
                                               const float* resid,
                                               int M, int N, int K) {
  __shared__ __align__(16) short As[128][72];
  __shared__ __align__(16) short Bs[128][72];
  const int t = threadIdx.x;
  const int m0 = blockIdx.x * 128, n0 = blockIdx.y * 128;
  const int wave = t >> 6, lane = t & 63, lr = lane & 15, lg = lane >> 4;
  const int wr = (wave >> 1) * 64, wc = (wave & 1) * 64;

  f32x4 acc[4][4];
  const f32x4 z4 = {0.f, 0.f, 0.f, 0.f};
  #pragma unroll
  for (int m = 0; m < 4; ++m)
    #pragma unroll
    for (int n = 0; n < 4; ++n) acc[m][n] = z4;

  int ar[4], ac[4];
  #pragma unroll
  for (int i = 0; i < 4; ++i) { int u = t + 256*i; ar[i] = u >> 3; ac[i] = (u & 7) * 8; }

  for (int k0 = 0; k0 < K; k0 += 64) {
    #pragma unroll
    for (int i = 0; i < 4; ++i) {
      uint4 va = *(const uint4*)(A + (size_t)(m0 + ar[i]) * K + k0 + ac[i]);
      *(uint4*)&As[ar[i]][ac[i]] = va;
    }
    #pragma unroll
    for (int i = 0; i < 4; ++i) {
      const float4* bp = (const float4*)(B + (size_t)(n0 + ar[i]) * K + k0 + ac[i]);
      float4 b0 = bp[0], b1 = bp[1];
      short8 pb = { f2bf(b0.x), f2bf(b0.y), f2bf(b0.z), f2bf(b0.w),
                    f2bf(b1.x), f2bf(b1.y), f2bf(b1.z), f2bf(b1.w) };
      *(short8*)&Bs[ar[i]][ac[i]] = pb;
    }
    __syncthreads();
    #pragma unroll
    for (int kk = 0; kk < 64; kk += 32) {
      short8 af[4], bfr[4];
      #pragma unroll
      for (int m = 0; m < 4; ++m) af[m]  = *(const short8*)&As[wr + m*16 + lr][kk + lg*8];
      #pragma unroll
      for (int n = 0; n < 4; ++n) bfr[n] = *(const short8*)&Bs[wc + n*16 + lr][kk + lg*8];
      #pragma unroll
      for (int m = 0; m < 4; ++m)
        #pragma unroll
        for (int n = 0; n < 4; ++n)
          acc[m][n] = MF(af[m], bfr[n], acc[m][n]);
    }
    __syncthreads();
  }

  #pragma unroll
  for (int m = 0; m < 4; ++m)
    #pragma unroll
    for (int n = 0; n < 4; ++n)
      #pragma unroll
      for (int r = 0; r < 4; ++r) {
        int row = m0 + wr + m*16 + lg*4 + r;
        int col = n0 + wc + n*16 + lr;
        size_t idx = (size_t)row * N + col;
        float vv = acc[m][n][r];
        if (EPI == 0) {
          ((short*)Cv)[idx] = f2bf(vv);
        } else if (EPI == 1) {
          float gl = 0.5f * vv * (1.0f + erff(vv * 0.70710678118654752f));
          ((short*)Cv)[idx] = f2bf(gl);
        } else {
          ((float*)Cv)[idx] = vv + resid[idx];
        }
      }
}

__global__ __launch_bounds__(256) void attn_k(const short* __restrict__ Q,
                                              const short* __restrict__ K,
                                              const short* __restrict__ V,
                                              short* __restrict__ O) {
  const float scale = 0.08838834764831845f;
  const int qt = blockIdx.x;
  const int bh = blockIdx.y;
  const int b = bh >> 4, h = bh & 15;
  const size_t base = ((size_t)b * SEQ) * D_MODEL + (size_t)h * DK;
  const int t = threadIdx.x, wave = t >> 6, lane = t & 63, lr = lane & 15, lg = lane >> 4;

  __shared__ __align__(16) short Ks[32][136];
  __shared__ __align__(16) short Vt[128][40];
  __shared__ __align__(16) short Ps[4][32][40];

  const int qrow0 = qt * 128 + wave * 32;
  short8 qf[2][4];
  #pragma unroll
  for (int mq = 0; mq < 2; ++mq)
    #pragma unroll
    for (int ki = 0; ki < 4; ++ki)
      qf[mq][ki] = *(const short8*)(Q + base + (size_t)(qrow0 + mq*16 + lr) * D_MODEL + ki*32 + lg*8);

  f32x4 acc[2][8];
  const f32x4 z4 = {0.f, 0.f, 0.f, 0.f};
  #pragma unroll
  for (int mq = 0; mq < 2; ++mq)
    #pragma unroll
    for (int nd = 0; nd < 8; ++nd) acc[mq][nd] = z4;
  float mrow[2][4], lsum[2][4];
  #pragma unroll
  for (int mq = 0; mq < 2; ++mq)
    #pragma unroll
    for (int r = 0; r < 4; ++r) { mrow[mq][r] = -INFINITY; lsum[mq][r] = 0.f; }

  const int lastt = qt * 4 + 3;
  for (int tt = 0; tt <= lastt; ++tt) {
    #pragma unroll
    for (int i = 0; i < 2; ++i) {
      int u = t + 256*i; int r = u >> 4; int c = (u & 15) * 8;
      *(uint4*)&Ks[r][c] = *(const uint4*)(K + base + (size_t)(tt*32 + r) * D_MODEL + c);
      uint4 vv = *(const uint4*)(V + base + (size_t)(tt*32 + r) * D_MODEL + c);
      const short* sv = (const short*)&vv;
      #pragma unroll
      for (int j = 0; j < 8; ++j) Vt[c + j][r] = sv[j];
    }
    __syncthreads();
    if (tt <= qt * 4 + wave) {
      f32x4 sf[2][2] = {{z4, z4}, {z4, z4}};
      #pragma unroll
      for (int ki = 0; ki < 4; ++ki) {
        short8 kf0 = *(const short8*)&Ks[lr][ki*32 + lg*8];
        short8 kf1 = *(const short8*)&Ks[16 + lr][ki*32 + lg*8];
        sf[0][0] = MF(qf[0][ki], kf0, sf[0][0]);
        sf[0][1] = MF(qf[0][ki], kf1, sf[0][1]);
        sf[1][0] = MF(qf[1][ki], kf0, sf[1][0]);
        sf[1][1] = MF(qf[1][ki], kf1, sf[1][1]);
      }
      #pragma unroll
      for (int mq = 0; mq < 2; ++mq) {
        #pragma unroll
        for (int r = 0; r < 4; ++r) {
          int qg = qrow0 + mq*16 + lg*4 + r;
          float s0 = sf[mq][0][r] * scale;
          float s1 = sf[mq][1][r] * scale;
          if (tt*32 + lr > qg)       s0 = -INFINITY;
          if (tt*32 + 16 + lr > qg)  s1 = -INFINITY;
          float mx = fmaxf(s0, s1);
          mx = fmaxf(mx, __shfl_xor(mx, 1));
          mx = fmaxf(mx, __shfl_xor(mx, 2));
          mx = fmaxf(mx, __shfl_xor(mx, 4));
          mx = fmaxf(mx, __shfl_xor(mx, 8));
          float mnew = fmaxf(mrow[mq][r], mx);
          float alpha = __expf(mrow[mq][r] - mnew);
          mrow[mq][r] = mnew;
          float p0 = __expf(s0 - mnew);
          float p1 = __expf(s1 - mnew);
          float ps = p0 + p1;
          ps += __shfl_xor(ps, 1);
          ps += __shfl_xor(ps, 2);
          ps += __shfl_xor(ps, 4);
          ps += __shfl_xor(ps, 8);
          lsum[mq][r] = lsum[mq][r] * alpha + ps;
          #pragma unroll
          for (int nd = 0; nd < 8; ++nd) acc[mq][nd][r] *= alpha;
          Ps[wave][mq*16 + lg*4 + r][lr]      = f2bf(p0);
          Ps[wave][mq*16 + lg*4 + r][16 + lr] = f2bf(p1);
        }
      }
      asm volatile("s_waitcnt lgkmcnt(0)" ::: "memory");
      short8 pf0 = *(const short8*)&Ps[wave][lr][lg*8];
      short8 pf1 = *(const short8*)&Ps[wave][16 + lr][lg*8];
      #pragma unroll
      for (int nd = 0; nd < 8; ++nd) {
        short8 vf = *(const short8*)&Vt[nd*16 + lr][lg*8];
        acc[0][nd] = MF(pf0, vf, acc[0][nd]);
        acc[1][nd] = MF(pf1, vf, acc[1][nd]);
      }
    }
    __syncthreads();
  }

  #pragma unroll
  for (int mq = 0; mq < 2; ++mq)
    #pragma unroll
    for (int nd = 0; nd < 8; ++nd)
      #pragma unroll
      for (int r = 0; r < 4; ++r) {
        int row = qrow0 + mq*16 + lg*4 + r;
        O[base + (size_t)row * D_MODEL + nd*16 + lr] = f2bf(acc[mq][nd][r] / lsum[mq][r]);
      }
}

// ---------------- launch ----------------
extern "C" void kernel_launch(void* const* d_in, const int* in_sizes, int n_in,
                              void* d_out, int out_size, void* d_ws, size_t ws_size,
                              hipStream_t stream) {
  const float* x  = (const float*)d_in[0];
  const float* wq = (const float*)d_in[1];
  const float* wk = (const float*)d_in[2];
  const float* wv = (const float*)d_in[3];
  const float* wo = (const float*)d_in[4];
  const float* w1 = (const float*)d_in[5];
  const float* w2 = (const float*)d_in[6];
  const float* g1 = (const float*)d_in[7];
  const float* g2 = (const float*)d_in[8];
  float* out = (float*)d_out;
  char* ws = (char*)d_ws;

  const size_t NEED = (size_t)192 << 20;
  if (ws_size >= NEED) {
    // fast path layout (192 MiB): see round-3 notes
    short* wqkv = (short*)(ws);
    short* wo_b = (short*)(ws + ((size_t)24 << 20));
    short* w1_b = (short*)(ws + ((size_t)32 << 20));
    short* w2_b = (short*)(ws + ((size_t)64 << 20));
    short* qkv  = (short*)(ws + ((size_t)96 << 20));
    short* vt   = (short*)(ws + ((size_t)144 << 20));
    short* ab   = (short*)(ws + ((size_t)160 << 20));
    short* xn   = (short*)(ws + ((size_t)176 << 20));
    short* hb   = (short*)(ws + ((size_t)96 << 20));

    const int NW = D_MODEL * D_MODEL / 8;
    f2b_k<<<(NW + 255) / 256, 256, 0, stream>>>(wq, wqkv,                   NW);
    f2b_k<<<(NW + 255) / 256, 256, 0, stream>>>(wk, wqkv + (size_t)D_MODEL * D_MODEL,     NW);
    f2b_k<<<(NW + 255) / 256, 256, 0, stream>>>(wv, wqkv + (size_t)2 * D_MODEL * D_MODEL, NW);
    f2b_k<<<(NW + 255) / 256, 256, 0, stream>>>(wo, wo_b, NW);
    const int NF = DFF * D_MODEL / 8;
    f2b_k<<<(NF + 255) / 256, 256, 0, stream>>>(w1, w1_b, NF);
    f2b_k<<<(NF + 255) / 256, 256, 0, stream>>>(w2, w2_b, NF);

    rmsnorm_k<<<MROWS, 256, 0, stream>>>(x, g1, xn);
    // QKV: M=4096, N=6144, K=2048 -> 32x24 = 768 blocks
    gemm8p<0><<<dim3(32 * 24), 512, 0, stream>>>(xn, wqkv, qkv, nullptr, MROWS, 6144, D_MODEL, 32);
    vtrans<<<dim3(SEQ/64, BATCH*NHEAD), 256, 0, stream>>>(qkv, vt);
    attn3<<<dim3(8, BATCH*NHEAD), 512, 0, stream>>>(qkv, vt, ab);
    // o-proj: N=2048 -> 32x8 = 256 blocks
    gemm8p<2><<<dim3(32 * 8), 512, 0, stream>>>(ab, wo_b, out, x, MROWS, D_MODEL, D_MODEL, 32);
    rmsnorm_k<<<MROWS, 256, 0, stream>>>(out, g2, xn);
    // FFN1: N=8192 -> 32x32 = 1024 blocks
    gemm8p<1><<<dim3(32 * 32), 512, 0, stream>>>(xn, w1_b, hb, nullptr, MROWS, DFF, D_MODEL, 32);
    // FFN2: N=2048, K=8192 -> 256 blocks
    gemm8p<2><<<dim3(32 * 8), 512, 0, stream>>>(hb, w2_b, out, out, MROWS, D_MODEL, DFF, 32);
  } else {
    // fallback: round-2 verified path (80 MiB)
    short* qb = (short*)(ws + ((size_t)0  << 20));
    short* kb = (short*)(ws + ((size_t)16 << 20));
    short* vb = (short*)(ws + ((size_t)32 << 20));
    short* ab = (short*)(ws + ((size_t)48 << 20));
    short* xn = (short*)(ws + ((size_t)64 << 20));
    short* hb = (short*)(ws + ((size_t)0  << 20));

    dim3 gproj(MROWS / 128, D_MODEL / 128);
    rmsnorm_k<<<MROWS, 256, 0, stream>>>(x, g1, xn);
    gemm_bt<0><<<gproj, 256, 0, stream>>>(xn, wq, qb, nullptr, MROWS, D_MODEL, D_MODEL);
    gemm_bt<0><<<gproj, 256, 0, stream>>>(xn, wk, kb, nullptr, MROWS, D_MODEL, D_MODEL);
    gemm_bt<0><<<gproj, 256, 0, stream>>>(xn, wv, vb, nullptr, MROWS, D_MODEL, D_MODEL);
    attn_k<<<dim3(SEQ / 128, BATCH * NHEAD), 256, 0, stream>>>(qb, kb, vb, ab);
    gemm_bt<2><<<gproj, 256, 0, stream>>>(ab, wo, out, x, MROWS, D_MODEL, D_MODEL);
    rmsnorm_k<<<MROWS, 256, 0, stream>>>(out, g2, xn);
    for (int half = 0; half < 2; ++half) {
      const short* xh = xn  + (size_t)half * 2048 * D_MODEL;
      float*       oh = out + (size_t)half * 2048 * D_MODEL;
      gemm_bt<1><<<dim3(2048 / 128, DFF / 128), 256, 0, stream>>>(xh, w1, hb, nullptr, 2048, DFF, D_MODEL);
      gemm_bt<2><<<dim3(2048 / 128, D_MODEL / 128), 256, 0, stream>>>(hb, w2, oh, oh, 2048, D_MODEL, DFF);
    }
  }
}

// Round 6
// 757.764 us; speedup vs baseline: 1.6793x; 1.0479x over previous
//
#include <hip/hip_runtime.h>
#include <hip/hip_bf16.h>
#include <math.h>

// ---- problem constants ----
#define D_MODEL 2048
#define SEQ     2048
#define BATCH   2
#define NHEAD   16
#define DK      128
#define DFF     8192
#define MROWS   (BATCH*SEQ)   // 4096 rows

typedef short short8 __attribute__((ext_vector_type(8)));   // 8 bf16 in 4 VGPRs
typedef float f32x4  __attribute__((ext_vector_type(4)));

__device__ __forceinline__ short f2bf(float f) {
  union { __hip_bfloat16 b; short s; } u;
  u.b = __float2bfloat16(f);
  return u.s;
}

#define MF(a, b, c) __builtin_amdgcn_mfma_f32_16x16x32_bf16(a, b, c, 0, 0, 0)
#define BAR()   asm volatile("s_barrier" ::: "memory")
#define LGKM0() { asm volatile("s_waitcnt lgkmcnt(0)" ::: "memory"); __builtin_amdgcn_sched_barrier(0); }
// wave-uniform LDS base via m0, per-lane global addr, 16B/lane direct-to-LDS
#define STG(gptr, ldsbyte) { \
    unsigned _m0v = (unsigned)__builtin_amdgcn_readfirstlane((int)(ldsbyte)); \
    asm volatile("s_mov_b32 m0, %1\n\tglobal_load_lds_dwordx4 %0, off" \
                 :: "v"(gptr), "s"(_m0v) : "memory"); }

// ---------------- RMSNorm: fp32 in -> bf16 out ----------------
__global__ __launch_bounds__(256) void rmsnorm_k(const float* __restrict__ x,
                                                 const float* __restrict__ g,
                                                 short* __restrict__ o) {
  const int row = blockIdx.x;
  const int t = threadIdx.x;
  const float4* xr = (const float4*)(x + (size_t)row * D_MODEL);
  const float4* gr = (const float4*)g;
  float4 v0 = xr[2*t], v1 = xr[2*t+1];
  float s = v0.x*v0.x + v0.y*v0.y + v0.z*v0.z + v0.w*v0.w
          + v1.x*v1.x + v1.y*v1.y + v1.z*v1.z + v1.w*v1.w;
  #pragma unroll
  for (int off = 1; off < 64; off <<= 1) s += __shfl_xor(s, off);
  __shared__ float red[4];
  if ((t & 63) == 0) red[t >> 6] = s;
  __syncthreads();
  float tot = red[0] + red[1] + red[2] + red[3];
  float inv = rsqrtf(tot * (1.0f / D_MODEL) + 1e-5f);
  float4 g0 = gr[2*t], g1v = gr[2*t+1];
  short8 ov;
  ov[0] = f2bf(v0.x * inv * g0.x);
  ov[1] = f2bf(v0.y * inv * g0.y);
  ov[2] = f2bf(v0.z * inv * g0.z);
  ov[3] = f2bf(v0.w * inv * g0.w);
  ov[4] = f2bf(v1.x * inv * g1v.x);
  ov[5] = f2bf(v1.y * inv * g1v.y);
  ov[6] = f2bf(v1.z * inv * g1v.z);
  ov[7] = f2bf(v1.w * inv * g1v.w);
  *((short8*)(o + (size_t)row * D_MODEL) + t) = ov;
}

// ---------------- fp32 -> bf16 convert (weights, one-time) ----------------
__global__ __launch_bounds__(256) void f2b_k(const float* __restrict__ src,
                                             short* __restrict__ dst, int n8) {
  int i = blockIdx.x * 256 + threadIdx.x;
  if (i >= n8) return;
  const float4* s4 = (const float4*)src + 2 * (size_t)i;
  float4 a = s4[0], b = s4[1];
  short8 o = { f2bf(a.x), f2bf(a.y), f2bf(a.z), f2bf(a.w),
               f2bf(b.x), f2bf(b.y), f2bf(b.z), f2bf(b.w) };
  *((short8*)dst + i) = o;
}

// ---------------- split-K combine: o = p0 + p1 + r (fp32) ----------------
__global__ __launch_bounds__(256) void combine_k(const float* p0, const float* p1,
                                                 const float* r, float* o, int n4) {
  int i = blockIdx.x * 256 + threadIdx.x;
  if (i >= n4) return;
  const float4 a = ((const float4*)p0)[i];
  const float4 b = ((const float4*)p1)[i];
  const float4 c = ((const float4*)r)[i];
  float4 d;
  d.x = a.x + b.x + c.x; d.y = a.y + b.y + c.y;
  d.z = a.z + b.z + c.z; d.w = a.w + b.w + c.w;
  ((float4*)o)[i] = d;
}

// ======== 256x256 8-phase counted-vmcnt GEMM (m201-style) ========
// C[M,N] = A[M,K](bf16) * B[N,K](bf16)^T. 512 thr = 8 waves (2M x 4N), wave 128x64.
// LDS: As/Bs [slot][half][128x64], 128 KB. Per K-tile (BK=64): 4 phases x 16 MFMA.
// Phase reads: ph1 B(k0,k1)+A(m0-3,k0)=12, ph2 A(m4-7,k0)+A(m0-3,k1)=8, ph3 A(m4-7,k1)=4, ph4 none.
// Region death: B after ph1, A after ph3. Stage stream (1 half/phase):
//   ph1 -> A-h1(T+1) [other slot]; ph2 -> B-h0(T+2); ph3 -> B-h1(T+2); ph4 -> A-h0(T+2).
// Boundary: vmcnt(6) (3 halves in flight) -> tile T+1 fully landed, never drains.
// EPI: 0 bf16; 1 GELU bf16; 2 +resid fp32; 3 plain fp32. SPLIT: in-dispatch split-K x2.
template<int EPI, int SPLIT>
__global__ __launch_bounds__(512, 2) void gemm256(const short* __restrict__ A,
                                                  const short* __restrict__ Bp,
                                                  void* Cv,
                                                  const float* __restrict__ resid,
                                                  int M, int N, int K,
                                                  int lda, int ldb, int nbx) {
  __shared__ __align__(16) short As[2][2][128 * 64];   // 64 KB
  __shared__ __align__(16) short Bs[2][2][128 * 64];   // 64 KB
  const int nk = K >> 6;
  const int cpx = gridDim.x >> 3;
  const int lin = (blockIdx.x & 7) * cpx + (blockIdx.x >> 3);
  const int bx = lin % nbx;
  int row2 = lin / nbx, by, ks = 0;
  if (SPLIT) { ks = row2 & 1; by = row2 >> 1; } else { by = row2; }
  const int m0 = bx * 256, n0 = by * 256;
  if (SPLIT) { A += (size_t)ks * K; Bp += (size_t)ks * K; }

  const int t = threadIdx.x, w = t >> 6, lane = t & 63, lr = lane & 15, lg = lane >> 4;
  const int wm = w >> 2, wn = w & 3;
  const unsigned aByte = (unsigned)(size_t)(const __attribute__((address_space(3))) short*)&As[0][0][0];
  const unsigned bByte = (unsigned)(size_t)(const __attribute__((address_space(3))) short*)&Bs[0][0][0];
  const unsigned wOff = (unsigned)(w * 1024);

  // staging geometry: thread t covers rows r and r+64, col-chunk c8, pre-swizzled source
  const int r = t >> 3, c8 = t & 7;
  const int sw = (c8 ^ (r & 7)) << 3;                 // (r+64)&7 == r&7
  const short* pA0 = A  + (size_t)(m0 + r)       * lda + sw;
  const short* pA1 = A  + (size_t)(m0 + 128 + r) * lda + sw;
  const short* pB0 = Bp + (size_t)(n0 + r)       * ldb + sw;
  const short* pB1 = Bp + (size_t)(n0 + 128 + r) * ldb + sw;
  const size_t l64A = (size_t)64 * lda, l64B = (size_t)64 * ldb;

  f32x4 acc[8][4];
  const f32x4 z4 = {0.f, 0.f, 0.f, 0.f};
  #pragma unroll
  for (int m = 0; m < 8; ++m)
    #pragma unroll
    for (int n = 0; n < 4; ++n) acc[m][n] = z4;

  // ---- prologue: A0h0, A0h1, B0h0, B0h1, B1h0, B1h1, A1h0 (order = vmcnt stream) ----
  STG(pA0,        aByte + wOff);                 STG(pA0 + l64A,      aByte + 8192 + wOff);
  STG(pA1,        aByte + 16384 + wOff);         STG(pA1 + l64A,      aByte + 16384 + 8192 + wOff);
  STG(pB0,        bByte + wOff);                 STG(pB0 + l64B,      bByte + 8192 + wOff);
  STG(pB1,        bByte + 16384 + wOff);         STG(pB1 + l64B,      bByte + 16384 + 8192 + wOff);
  if (nk > 1) {
    STG(pB0 + 64, bByte + 32768 + wOff);         STG(pB0 + 64 + l64B, bByte + 32768 + 8192 + wOff);
    STG(pB1 + 64, bByte + 32768 + 16384 + wOff); STG(pB1 + 64 + l64B, bByte + 32768 + 16384 + 8192 + wOff);
    STG(pA0 + 64, aByte + 32768 + wOff);         STG(pA0 + 64 + l64A, aByte + 32768 + 8192 + wOff);
    asm volatile("s_waitcnt vmcnt(6)" ::: "memory");
  } else {
    asm volatile("s_waitcnt vmcnt(0)" ::: "memory");
  }
  BAR();

  for (int T = 0; T < nk; ++T) {
    const int p = T & 1, q = p ^ 1;
    const unsigned aS = aByte + (unsigned)p * 32768u, aQ = aByte + (unsigned)q * 32768u;
    const unsigned bS = bByte + (unsigned)p * 32768u;

    // ---- ph1: stage A-h1(T+1) -> slot q; read B k0&k1 + A m0-3 k0; MFMA m0-3 x k0 ----
    if (T + 1 < nk) {
      const short* s = pA1 + (size_t)(T + 1) * 64;
      STG(s, aQ + 16384u + wOff); STG(s + l64A, aQ + 16384u + 8192u + wOff);
    }
    short8 bk0[4], bk1[4], aA[4];
    #pragma unroll
    for (int n = 0; n < 4; ++n) {
      int br = wn * 64 + n * 16 + lr;
      const short* bp = &Bs[p][br >> 7][(br & 127) * 64];
      bk0[n] = *(const short8*)&bp[(lg * 8)      ^ ((br & 7) << 3)];
      bk1[n] = *(const short8*)&bp[(32 + lg * 8) ^ ((br & 7) << 3)];
    }
    #pragma unroll
    for (int m = 0; m < 4; ++m) {
      int ar = m * 16 + lr;
      aA[m] = *(const short8*)&As[p][wm][ar * 64 + ((lg * 8) ^ ((ar & 7) << 3))];
    }
    BAR(); LGKM0();
    __builtin_amdgcn_s_setprio(1);
    #pragma unroll
    for (int m = 0; m < 4; ++m)
      #pragma unroll
      for (int n = 0; n < 4; ++n) acc[m][n] = MF(aA[m], bk0[n], acc[m][n]);
    __builtin_amdgcn_s_setprio(0);
    BAR();

    // ---- ph2: stage B-h0(T+2) -> slot p; read A m4-7 k0 + A m0-3 k1; MFMA m4-7 x k0 ----
    if (T + 2 < nk) {
      const short* s = pB0 + (size_t)(T + 2) * 64;
      STG(s, bS + wOff); STG(s + l64B, bS + 8192u + wOff);
    }
    short8 aB[4], aC[4];
    #pragma unroll
    for (int m = 0; m < 4; ++m) {
      int ar = 64 + m * 16 + lr;
      aB[m] = *(const short8*)&As[p][wm][ar * 64 + ((lg * 8) ^ ((ar & 7) << 3))];
      int ar2 = m * 16 + lr;
      aC[m] = *(const short8*)&As[p][wm][ar2 * 64 + ((32 + lg * 8) ^ ((ar2 & 7) << 3))];
    }
    BAR(); LGKM0();
    __builtin_amdgcn_s_setprio(1);
    #pragma unroll
    for (int m = 0; m < 4; ++m)
      #pragma unroll
      for (int n = 0; n < 4; ++n) acc[m + 4][n] = MF(aB[m], bk0[n], acc[m + 4][n]);
    __builtin_amdgcn_s_setprio(0);
    BAR();

    // ---- ph3: stage B-h1(T+2) -> slot p; read A m4-7 k1; MFMA m0-3 x k1 ----
    if (T + 2 < nk) {
      const short* s = pB1 + (size_t)(T + 2) * 64;
      STG(s, bS + 16384u + wOff); STG(s + l64B, bS + 16384u + 8192u + wOff);
    }
    short8 aD[4];
    #pragma unroll
    for (int m = 0; m < 4; ++m) {
      int ar = 64 + m * 16 + lr;
      aD[m] = *(const short8*)&As[p][wm][ar * 64 + ((32 + lg * 8) ^ ((ar & 7) << 3))];
    }
    BAR(); LGKM0();
    __builtin_amdgcn_s_setprio(1);
    #pragma unroll
    for (int m = 0; m < 4; ++m)
      #pragma unroll
      for (int n = 0; n < 4; ++n) acc[m][n] = MF(aC[m], bk1[n], acc[m][n]);
    __builtin_amdgcn_s_setprio(0);
    BAR();

    // ---- ph4: stage A-h0(T+2) -> slot p; MFMA m4-7 x k1 ----
    if (T + 2 < nk) {
      const short* s = pA0 + (size_t)(T + 2) * 64;
      STG(s, aS + wOff); STG(s + l64A, aS + 8192u + wOff);
    }
    BAR(); LGKM0();
    __builtin_amdgcn_s_setprio(1);
    #pragma unroll
    for (int m = 0; m < 4; ++m)
      #pragma unroll
      for (int n = 0; n < 4; ++n) acc[m + 4][n] = MF(aD[m], bk1[n], acc[m + 4][n]);
    __builtin_amdgcn_s_setprio(0);

    // ---- boundary: tile T+1 must be fully landed; keep 3 halves in flight ----
    if (T + 2 < nk)      { asm volatile("s_waitcnt vmcnt(6)" ::: "memory"); BAR(); }
    else if (T + 1 < nk) { asm volatile("s_waitcnt vmcnt(0)" ::: "memory"); BAR(); }
  }

  // ---- epilogue ----
  float* Cf = (float*)Cv;
  if (SPLIT) Cf += (size_t)ks * ((size_t)M * N);
  #pragma unroll
  for (int m = 0; m < 8; ++m)
    #pragma unroll
    for (int n = 0; n < 4; ++n)
      #pragma unroll
      for (int rr = 0; rr < 4; ++rr) {
        int row = m0 + wm * 128 + m * 16 + lg * 4 + rr;
        int col = n0 + wn * 64 + n * 16 + lr;
        size_t idx = (size_t)row * N + col;
        float vv = acc[m][n][rr];
        if (EPI == 0) {
          ((short*)Cv)[idx] = f2bf(vv);
        } else if (EPI == 1) {
          float gl = 0.5f * vv * (1.0f + erff(vv * 0.70710678118654752f));
          ((short*)Cv)[idx] = f2bf(gl);
        } else if (EPI == 2) {
          ((float*)Cv)[idx] = vv + resid[idx];
        } else {
          Cf[idx] = vv;
        }
      }
}

// ---------------- V transpose: qkv[.., v cols] -> vt[b][h][d][s] ----------------
__global__ __launch_bounds__(256) void vtrans(const short* __restrict__ QKV,
                                              short* __restrict__ VT) {
  const int st = blockIdx.x;   // s tile of 64
  const int bh = blockIdx.y;
  const int b = bh >> 4, h = bh & 15;
  const int t = threadIdx.x;
  __shared__ __align__(16) short T[64 * 128];
  const short* Vsrc = QKV + ((size_t)b * SEQ) * 6144 + 2 * D_MODEL + h * DK;
  {
    int r = t >> 4, c = (t & 15) * 8;
    #pragma unroll
    for (int i = 0; i < 4; ++i) {
      int rr = r + 16 * i;
      uint4 vv = *(const uint4*)(Vsrc + (size_t)(st * 64 + rr) * 6144 + c);
      *(uint4*)&T[rr * 128 + (c ^ (((rr >> 3) & 7) << 3))] = vv;
    }
  }
  __syncthreads();
  short* dst = VT + ((size_t)bh * DK) * SEQ + st * 64;
  {
    int c2 = (t & 7) * 8;
    #pragma unroll
    for (int i = 0; i < 4; ++i) {
      int d = (t >> 3) + 32 * i;
      short8 ov;
      #pragma unroll
      for (int j = 0; j < 8; ++j)
        ov[j] = T[(c2 + j) * 128 + (d ^ ((((c2 + j) >> 3) & 7) << 3))];
      *(short8*)(dst + (size_t)d * SEQ + c2) = ov;
    }
  }
}

// ---------------- Flash attention v3 (round-4 verified) ----------------
__global__ __launch_bounds__(512, 2) void attn3(const short* __restrict__ QKV,
                                                const short* __restrict__ VT,
                                                short* __restrict__ O) {
  const float SC = 0.12751743f;   // (1/sqrt(128)) * log2(e)
  const int a = blockIdx.x, bh = blockIdx.y;
  const int b = bh >> 4, h = bh & 15;
  const int t = threadIdx.x, w = t >> 6, lane = t & 63, lr = lane & 15, lg = lane >> 4;
  const short* Qp = QKV + ((size_t)b * SEQ) * 6144 + h * DK;
  const short* Kp = Qp + D_MODEL;
  const short* Vp = VT + ((size_t)bh * DK) * SEQ;   // [d][s]
  __shared__ __align__(16) short Ks[2][64 * 128];
  __shared__ __align__(16) short Vs[2][128 * 64];
  __shared__ __align__(16) short Ps[8][16][72];

  const int krr = t >> 4, kcc = (t & 15) * 8;
  const int vdd = t >> 3, vcc = (t & 7) * 8;
  const f32x4 z4 = {0.f, 0.f, 0.f, 0.f};

  for (int sub = 0; sub < 2; ++sub) {
    const int ts = sub ? (15 - a) : a;
    const int nt = 2 * ts + 2;
    const int qrow0 = ts * 128 + w * 16;

    short8 qf[4];
    #pragma unroll
    for (int ki = 0; ki < 4; ++ki)
      qf[ki] = *(const short8*)(Qp + (size_t)(qrow0 + lr) * 6144 + ki * 32 + lg * 8);

    f32x4 acc[8];
    #pragma unroll
    for (int nd = 0; nd < 8; ++nd) acc[nd] = z4;
    float mrow[4], lsum[4];
    #pragma unroll
    for (int r = 0; r < 4; ++r) { mrow[r] = -INFINITY; lsum[r] = 0.f; }

    uint4 krg[2], vrg[2];
    #pragma unroll
    for (int i = 0; i < 2; ++i) {
      krg[i] = *(const uint4*)(Kp + (size_t)(krr + 32 * i) * 6144 + kcc);
      vrg[i] = *(const uint4*)(Vp + (size_t)(vdd + 64 * i) * SEQ + vcc);
    }
    __syncthreads();
    #pragma unroll
    for (int i = 0; i < 2; ++i) {
      int r = krr + 32 * i;
      *(uint4*)&Ks[0][(r * 128 + kcc) ^ ((r & 7) << 3)] = krg[i];
      int d = vdd + 64 * i;
      *(uint4*)&Vs[0][(d * 64 + vcc) ^ ((d & 7) << 3)] = vrg[i];
    }
    __syncthreads();

    int cur = 0;
    for (int tt = 0; tt < nt; ++tt) {
      const bool pre = (tt + 1 < nt);
      if (pre) {
        #pragma unroll
        for (int i = 0; i < 2; ++i) {
          krg[i] = *(const uint4*)(Kp + (size_t)((tt + 1) * 64 + krr + 32 * i) * 6144 + kcc);
          vrg[i] = *(const uint4*)(Vp + (size_t)(vdd + 64 * i) * SEQ + (tt + 1) * 64 + vcc);
        }
      }

      f32x4 sf[4] = {z4, z4, z4, z4};
      #pragma unroll
      for (int ki = 0; ki < 4; ++ki) {
        #pragma unroll
        for (int nk = 0; nk < 4; ++nk) {
          int rr = nk * 16 + lr;
          short8 kf = *(const short8*)&Ks[cur][(rr * 128 + ki * 32 + lg * 8) ^ ((rr & 7) << 3)];
          sf[nk] = MF(qf[ki], kf, sf[nk]);
        }
      }

      const bool diag = (tt * 64 + 63 > qrow0);
      #pragma unroll
      for (int r = 0; r < 4; ++r) {
        int qg = qrow0 + lg * 4 + r;
        float s0 = sf[0][r] * SC, s1 = sf[1][r] * SC, s2 = sf[2][r] * SC, s3 = sf[3][r] * SC;
        if (diag) {
          int c0 = tt * 64 + lr;
          s0 = (c0      <= qg) ? s0 : -3.0e38f;
          s1 = (c0 + 16 <= qg) ? s1 : -3.0e38f;
          s2 = (c0 + 32 <= qg) ? s2 : -3.0e38f;
          s3 = (c0 + 48 <= qg) ? s3 : -3.0e38f;
        }
        float mx = fmaxf(fmaxf(s0, s1), fmaxf(s2, s3));
        mx = fmaxf(mx, __shfl_xor(mx, 1));
        mx = fmaxf(mx, __shfl_xor(mx, 2));
        mx = fmaxf(mx, __shfl_xor(mx, 4));
        mx = fmaxf(mx, __shfl_xor(mx, 8));
        float mnew = fmaxf(mrow[r], mx);
        float alpha = exp2f(mrow[r] - mnew);
        mrow[r] = mnew;
        float p0 = exp2f(s0 - mnew), p1 = exp2f(s1 - mnew),
              p2 = exp2f(s2 - mnew), p3 = exp2f(s3 - mnew);
        lsum[r] = lsum[r] * alpha + ((p0 + p1) + (p2 + p3));
        #pragma unroll
        for (int nd = 0; nd < 8; ++nd) acc[nd][r] *= alpha;
        short* pr = &Ps[w][lg * 4 + r][0];
        pr[lr]      = f2bf(p0);
        pr[16 + lr] = f2bf(p1);
        pr[32 + lr] = f2bf(p2);
        pr[48 + lr] = f2bf(p3);
      }
      asm volatile("s_waitcnt lgkmcnt(0)" ::: "memory");
      __builtin_amdgcn_sched_barrier(0);

      short8 pf0 = *(const short8*)&Ps[w][lr][lg * 8];
      short8 pf1 = *(const short8*)&Ps[w][lr][32 + lg * 8];
      #pragma unroll
      for (int nd = 0; nd < 8; ++nd) {
        int rr = nd * 16 + lr;
        short8 vf0 = *(const short8*)&Vs[cur][(rr * 64 + lg * 8) ^ ((rr & 7) << 3)];
        short8 vf1 = *(const short8*)&Vs[cur][(rr * 64 + 32 + lg * 8) ^ ((rr & 7) << 3)];
        acc[nd] = MF(pf0, vf0, acc[nd]);
        acc[nd] = MF(pf1, vf1, acc[nd]);
      }
      __syncthreads();
      if (pre) {
        #pragma unroll
        for (int i = 0; i < 2; ++i) {
          int r = krr + 32 * i;
          *(uint4*)&Ks[cur ^ 1][(r * 128 + kcc) ^ ((r & 7) << 3)] = krg[i];
          int d = vdd + 64 * i;
          *(uint4*)&Vs[cur ^ 1][(d * 64 + vcc) ^ ((d & 7) << 3)] = vrg[i];
        }
      }
      __syncthreads();
      cur ^= 1;
    }

    float inv[4];
    #pragma unroll
    for (int r = 0; r < 4; ++r) {
      float ls = lsum[r];
      ls += __shfl_xor(ls, 1);
      ls += __shfl_xor(ls, 2);
      ls += __shfl_xor(ls, 4);
      ls += __shfl_xor(ls, 8);
      inv[r] = 1.0f / ls;
    }
    #pragma unroll
    for (int nd = 0; nd < 8; ++nd)
      #pragma unroll
      for (int r = 0; r < 4; ++r) {
        int row = qrow0 + lg * 4 + r;
        O[(size_t)(b * SEQ + row) * D_MODEL + h * DK + nd * 16 + lr] = f2bf(acc[nd][r] * inv[r]);
      }
  }
}

// ======== FALLBACK PATH (round-2 verified kernels) ========
template<int EPI>
__global__ __launch_bounds__(256) void gemm_bt(const short* __restrict__ A,
                                               const float* __restrict__ B,
                                               void* Cv,
                                               const float* resid,
                                               int M, int N, int K) {
  __shared__ __align__(16) short As[128][72];
  __shared__ __align__(16) short Bs[128][72];
  const int t = threadIdx.x;
  const int m0 = blockIdx.x * 128, n0 = blockIdx.y * 128;
  const int wave = t >> 6, lane = t & 63, lr = lane & 15, lg = lane >> 4;
  const int wr = (wave >> 1) * 64, wc = (wave & 1) * 64;

  f32x4 acc[4][4];
  const f32x4 z4 = {0.f, 0.f, 0.f, 0.f};
  #pragma unroll
  for (int m = 0; m < 4; ++m)
    #pragma unroll
    for (int n = 0; n < 4; ++n) acc[m][n] = z4;

  int ar[4], ac[4];
  #pragma unroll
  for (int i = 0; i < 4; ++i) { int u = t + 256*i; ar[i] = u >> 3; ac[i] = (u & 7) * 8; }

  for (int k0 = 0; k0 < K; k0 += 64) {
    #pragma unroll
    for (int i = 0; i < 4; ++i) {
      uint4 va = *(const uint4*)(A + (size_t)(m0 + ar[i]) * K + k0 + ac[i]);
      *(uint4*)&As[ar[i]][ac[i]] = va;
    }
    #pragma unroll
    for (int i = 0; i < 4; ++i) {
      const float4* bp = (const float4*)(B + (size_t)(n0 + ar[i]) * K + k0 + ac[i]);
      float4 b0 = bp[0], b1 = bp[1];
      short8 pb = { f2bf(b0.x), f2bf(b0.y), f2bf(b0.z), f2bf(b0.w),
                    f2bf(b1.x), f2bf(b1.y), f2bf(b1.z), f2bf(b1.w) };
      *(short8*)&Bs[ar[i]][ac[i]] = pb;
    }
    __syncthreads();
    #pragma unroll
    for (int kk = 0; kk < 64; kk += 32) {
      short8 af[4], bfr[4];
      #pragma unroll
      for (int m = 0; m < 4; ++m) af[m]  = *(const short8*)&As[wr + m*16 + lr][kk + lg*8];
      #pragma unroll
      for (int n = 0; n < 4; ++n) bfr[n] = *(const short8*)&Bs[wc + n*16 + lr][kk + lg*8];
      #pragma unroll
      for (int m = 0; m < 4; ++m)
        #pragma unroll
        for (int n = 0; n < 4; ++n)
          acc[m][n] = MF(af[m], bfr[n], acc[m][n]);
    }
    __syncthreads();
  }

  #pragma unroll
  for (int m = 0; m < 4; ++m)
    #pragma unroll
    for (int n = 0; n < 4; ++n)
      #pragma unroll
      for (int r = 0; r < 4; ++r) {
        int row = m0 + wr + m*16 + lg*4 + r;
        int col = n0 + wc + n*16 + lr;
        size_t idx = (size_t)row * N + col;
        float vv = acc[m][n][r];
        if (EPI == 0) {
          ((short*)Cv)[idx] = f2bf(vv);
        } else if (EPI == 1) {
          float gl = 0.5f * vv * (1.0f + erff(vv * 0.70710678118654752f));
          ((short*)Cv)[idx] = f2bf(gl);
        } else {
          ((float*)Cv)[idx] = vv + resid[idx];
        }
      }
}

__global__ __launch_bounds__(256) void attn_k(const short* __restrict__ Q,
                                              const short* __restrict__ K,
                                              const short* __restrict__ V,
                                              short* __restrict__ O) {
  const float scale = 0.08838834764831845f;
  const int qt = blockIdx.x;
  const int bh = blockIdx.y;
  const int b = bh >> 4, h = bh & 15;
  const size_t base = ((size_t)b * SEQ) * D_MODEL + (size_t)h * DK;
  const int t = threadIdx.x, wave = t >> 6, lane = t & 63, lr = lane & 15, lg = lane >> 4;

  __shared__ __align__(16) short Ks[32][136];
  __shared__ __align__(16) short Vt[128][40];
  __shared__ __align__(16) short Ps[4][32][40];

  const int qrow0 = qt * 128 + wave * 32;
  short8 qf[2][4];
  #pragma unroll
  for (int mq = 0; mq < 2; ++mq)
    #pragma unroll
    for (int ki = 0; ki < 4; ++ki)
      qf[mq][ki] = *(const short8*)(Q + base + (size_t)(qrow0 + mq*16 + lr) * D_MODEL + ki*32 + lg*8);

  f32x4 acc[2][8];
  const f32x4 z4 = {0.f, 0.f, 0.f, 0.f};
  #pragma unroll
  for (int mq = 0; mq < 2; ++mq)
    #pragma unroll
    for (int nd = 0; nd < 8; ++nd) acc[mq][nd] = z4;
  float mrow[2][4], lsum[2][4];
  #pragma unroll
  for (int mq = 0; mq < 2; ++mq)
    #pragma unroll
    for (int r = 0; r < 4; ++r) { mrow[mq][r] = -INFINITY; lsum[mq][r] = 0.f; }

  const int lastt = qt * 4 + 3;
  for (int tt = 0; tt <= lastt; ++tt) {
    #pragma unroll
    for (int i = 0; i < 2; ++i) {
      int u = t + 256*i; int r = u >> 4; int c = (u & 15) * 8;
      *(uint4*)&Ks[r][c] = *(const uint4*)(K + base + (size_t)(tt*32 + r) * D_MODEL + c);
      uint4 vv = *(const uint4*)(V + base + (size_t)(tt*32 + r) * D_MODEL + c);
      const short* sv = (const short*)&vv;
      #pragma unroll
      for (int j = 0; j < 8; ++j) Vt[c + j][r] = sv[j];
    }
    __syncthreads();
    if (tt <= qt * 4 + wave) {
      f32x4 sf[2][2] = {{z4, z4}, {z4, z4}};
      #pragma unroll
      for (int ki = 0; ki < 4; ++ki) {
        short8 kf0 = *(const short8*)&Ks[lr][ki*32 + lg*8];
        short8 kf1 = *(const short8*)&Ks[16 + lr][ki*32 + lg*8];
        sf[0][0] = MF(qf[0][ki], kf0, sf[0][0]);
        sf[0][1] = MF(qf[0][ki], kf1, sf[0][1]);
        sf[1][0] = MF(qf[1][ki], kf0, sf[1][0]);
        sf[1][1] = MF(qf[1][ki], kf1, sf[1][1]);
      }
      #pragma unroll
      for (int mq = 0; mq < 2; ++mq) {
        #pragma unroll
        for (int r = 0; r < 4; ++r) {
          int qg = qrow0 + mq*16 + lg*4 + r;
          float s0 = sf[mq][0][r] * scale;
          float s1 = sf[mq][1][r] * scale;
          if (tt*32 + lr > qg)       s0 = -INFINITY;
          if (tt*32 + 16 + lr > qg)  s1 = -INFINITY;
          float mx = fmaxf(s0, s1);
          mx = fmaxf(mx, __shfl_xor(mx, 1));
          mx = fmaxf(mx, __shfl_xor(mx, 2));
          mx = fmaxf(mx, __shfl_xor(mx, 4));
          mx = fmaxf(mx, __shfl_xor(mx, 8));
          float mnew = fmaxf(mrow[mq][r], mx);
          float alpha = __expf(mrow[mq][r] - mnew);
          mrow[mq][r] = mnew;
          float p0 = __expf(s0 - mnew);
          float p1 = __expf(s1 - mnew);
          float ps = p0 + p1;
          ps += __shfl_xor(ps, 1);
          ps += __shfl_xor(ps, 2);
          ps += __shfl_xor(ps, 4);
          ps += __shfl_xor(ps, 8);
          lsum[mq][r] = lsum[mq][r] * alpha + ps;
          #pragma unroll
          for (int nd = 0; nd < 8; ++nd) acc[mq][nd][r] *= alpha;
          Ps[wave][mq*16 + lg*4 + r][lr]      = f2bf(p0);
          Ps[wave][mq*16 + lg*4 + r][16 + lr] = f2bf(p1);
        }
      }
      asm volatile("s_waitcnt lgkmcnt(0)" ::: "memory");
      short8 pf0 = *(const short8*)&Ps[wave][lr][lg*8];
      short8 pf1 = *(const short8*)&Ps[wave][16 + lr][lg*8];
      #pragma unroll
      for (int nd = 0; nd < 8; ++nd) {
        short8 vf = *(const short8*)&Vt[nd*16 + lr][lg*8];
        acc[0][nd] = MF(pf0, vf, acc[0][nd]);
        acc[1][nd] = MF(pf1, vf, acc[1][nd]);
      }
    }
    __syncthreads();
  }

  #pragma unroll
  for (int mq = 0; mq < 2; ++mq)
    #pragma unroll
    for (int nd = 0; nd < 8; ++nd)
      #pragma unroll
      for (int r = 0; r < 4; ++r) {
        int row = qrow0 + mq*16 + lg*4 + r;
        O[base + (size_t)row * D_MODEL + nd*16 + lr] = f2bf(acc[mq][nd][r] / lsum[mq][r]);
      }
}

// ---------------- launch ----------------
extern "C" void kernel_launch(void* const* d_in, const int* in_sizes, int n_in,
                              void* d_out, int out_size, void* d_ws, size_t ws_size,
                              hipStream_t stream) {
  const float* x  = (const float*)d_in[0];
  const float* wq = (const float*)d_in[1];
  const float* wk = (const float*)d_in[2];
  const float* wv = (const float*)d_in[3];
  const float* wo = (const float*)d_in[4];
  const float* w1 = (const float*)d_in[5];
  const float* w2 = (const float*)d_in[6];
  const float* g1 = (const float*)d_in[7];
  const float* g2 = (const float*)d_in[8];
  float* out = (float*)d_out;
  char* ws = (char*)d_ws;

  const size_t NEED = (size_t)192 << 20;
  if (ws_size >= NEED) {
    // fast path layout (192 MiB):
    //   [0,24M) wqkv | [24,32M) wo | [32,64M) w1 | [64,96M) w2   (bf16 weights)
    //   [96,144M) qkv | [144,160M) vt | [160,176M) ab | [176,192M) xn
    //   FFN phase: hb = [96,160M); FFN2 split-K partials = [160,192M) (ab/xn dead)
    short* wqkv = (short*)(ws);
    short* wo_b = (short*)(ws + ((size_t)24 << 20));
    short* w1_b = (short*)(ws + ((size_t)32 << 20));
    short* w2_b = (short*)(ws + ((size_t)64 << 20));
    short* qkv  = (short*)(ws + ((size_t)96 << 20));
    short* vt   = (short*)(ws + ((size_t)144 << 20));
    short* ab   = (short*)(ws + ((size_t)160 << 20));
    short* xn   = (short*)(ws + ((size_t)176 << 20));
    short* hb   = (short*)(ws + ((size_t)96 << 20));
    float* pf   = (float*)(ws + ((size_t)160 << 20));   // 2x 32MB fp32 partials

    const int NW = D_MODEL * D_MODEL / 8;
    f2b_k<<<(NW + 255) / 256, 256, 0, stream>>>(wq, wqkv,                   NW);
    f2b_k<<<(NW + 255) / 256, 256, 0, stream>>>(wk, wqkv + (size_t)D_MODEL * D_MODEL,     NW);
    f2b_k<<<(NW + 255) / 256, 256, 0, stream>>>(wv, wqkv + (size_t)2 * D_MODEL * D_MODEL, NW);
    f2b_k<<<(NW + 255) / 256, 256, 0, stream>>>(wo, wo_b, NW);
    const int NF = DFF * D_MODEL / 8;
    f2b_k<<<(NF + 255) / 256, 256, 0, stream>>>(w1, w1_b, NF);
    f2b_k<<<(NF + 255) / 256, 256, 0, stream>>>(w2, w2_b, NF);

    rmsnorm_k<<<MROWS, 256, 0, stream>>>(x, g1, xn);
    // QKV: 16x24 = 384 blocks
    gemm256<0,0><<<dim3(16 * 24), 512, 0, stream>>>(xn, wqkv, qkv, nullptr,
                                                    MROWS, 6144, D_MODEL, D_MODEL, D_MODEL, 16);
    vtrans<<<dim3(SEQ/64, BATCH*NHEAD), 256, 0, stream>>>(qkv, vt);
    attn3<<<dim3(8, BATCH*NHEAD), 512, 0, stream>>>(qkv, vt, ab);
    // o-proj: 16x8 = 128 blocks, +resid
    gemm256<2,0><<<dim3(16 * 8), 512, 0, stream>>>(ab, wo_b, out, x,
                                                   MROWS, D_MODEL, D_MODEL, D_MODEL, D_MODEL, 16);
    rmsnorm_k<<<MROWS, 256, 0, stream>>>(out, g2, xn);
    // FFN1: 16x32 = 512 blocks, GELU
    gemm256<1,0><<<dim3(16 * 32), 512, 0, stream>>>(xn, w1_b, hb, nullptr,
                                                    MROWS, DFF, D_MODEL, D_MODEL, D_MODEL, 16);
    // FFN2: split-K x2 in one dispatch (16x8x2 = 256 blocks), then combine with resid
    gemm256<3,1><<<dim3(16 * 8 * 2), 512, 0, stream>>>(hb, w2_b, pf, nullptr,
                                                       MROWS, D_MODEL, DFF / 2, DFF, DFF, 16);
    const int N4 = MROWS * D_MODEL / 4;
    combine_k<<<(N4 + 255) / 256, 256, 0, stream>>>(pf, pf + (size_t)MROWS * D_MODEL, out, out, N4);
  } else {
    // fallback: round-2 verified path (80 MiB)
    short* qb = (short*)(ws + ((size_t)0  << 20));
    short* kb = (short*)(ws + ((size_t)16 << 20));
    short* vb = (short*)(ws + ((size_t)32 << 20));
    short* ab = (short*)(ws + ((size_t)48 << 20));
    short* xn = (short*)(ws + ((size_t)64 << 20));
    short* hb = (short*)(ws + ((size_t)0  << 20));

    dim3 gproj(MROWS / 128, D_MODEL / 128);
    rmsnorm_k<<<MROWS, 256, 0, stream>>>(x, g1, xn);
    gemm_bt<0><<<gproj, 256, 0, stream>>>(xn, wq, qb, nullptr, MROWS, D_MODEL, D_MODEL);
    gemm_bt<0><<<gproj, 256, 0, stream>>>(xn, wk, kb, nullptr, MROWS, D_MODEL, D_MODEL);
    gemm_bt<0><<<gproj, 256, 0, stream>>>(xn, wv, vb, nullptr, MROWS, D_MODEL, D_MODEL);
    attn_k<<<dim3(SEQ / 128, BATCH * NHEAD), 256, 0, stream>>>(qb, kb, vb, ab);
    gemm_bt<2><<<gproj, 256, 0, stream>>>(ab, wo, out, x, MROWS, D_MODEL, D_MODEL);
    rmsnorm_k<<<MROWS, 256, 0, stream>>>(out, g2, xn);
    for (int half = 0; half < 2; ++half) {
      const short* xh = xn  + (size_t)half * 2048 * D_MODEL;
      float*       oh = out + (size_t)half * 2048 * D_MODEL;
      gemm_bt<1><<<dim3(2048 / 128, DFF / 128), 256, 0, stream>>>(xh, w1, hb, nullptr, 2048, DFF, D_MODEL);
      gemm_bt<2><<<dim3(2048 / 128, D_MODEL / 128), 256, 0, stream>>>(hb, w2, oh, oh, 2048, D_MODEL, DFF);
    }
  }
}

// Round 7
// 743.109 us; speedup vs baseline: 1.7125x; 1.0197x over previous
//
#include <hip/hip_runtime.h>
#include <hip/hip_bf16.h>
#include <math.h>

// ---- problem constants ----
#define D_MODEL 2048
#define SEQ     2048
#define BATCH   2
#define NHEAD   16
#define DK      128
#define DFF     8192
#define MROWS   (BATCH*SEQ)   // 4096 rows

typedef short short8 __attribute__((ext_vector_type(8)));   // 8 bf16 in 4 VGPRs
typedef float f32x4  __attribute__((ext_vector_type(4)));

__device__ __forceinline__ short f2bf(float f) {
  union { __hip_bfloat16 b; short s; } u;
  u.b = __float2bfloat16(f);
  return u.s;
}

#define MF(a, b, c) __builtin_amdgcn_mfma_f32_16x16x32_bf16(a, b, c, 0, 0, 0)
// wave-uniform LDS base via m0, per-lane global addr, 16B/lane direct-to-LDS
#define STG(gptr, ldsbyte) { \
    unsigned _m0v = (unsigned)__builtin_amdgcn_readfirstlane((int)(ldsbyte)); \
    asm volatile("s_mov_b32 m0, %1\n\tglobal_load_lds_dwordx4 %0, off" \
                 :: "v"(gptr), "s"(_m0v) : "memory"); }

// ---------------- RMSNorm: fp32 in -> bf16 out ----------------
__global__ __launch_bounds__(256) void rmsnorm_k(const float* __restrict__ x,
                                                 const float* __restrict__ g,
                                                 short* __restrict__ o) {
  const int row = blockIdx.x;
  const int t = threadIdx.x;
  const float4* xr = (const float4*)(x + (size_t)row * D_MODEL);
  const float4* gr = (const float4*)g;
  float4 v0 = xr[2*t], v1 = xr[2*t+1];
  float s = v0.x*v0.x + v0.y*v0.y + v0.z*v0.z + v0.w*v0.w
          + v1.x*v1.x + v1.y*v1.y + v1.z*v1.z + v1.w*v1.w;
  #pragma unroll
  for (int off = 1; off < 64; off <<= 1) s += __shfl_xor(s, off);
  __shared__ float red[4];
  if ((t & 63) == 0) red[t >> 6] = s;
  __syncthreads();
  float tot = red[0] + red[1] + red[2] + red[3];
  float inv = rsqrtf(tot * (1.0f / D_MODEL) + 1e-5f);
  float4 g0 = gr[2*t], g1v = gr[2*t+1];
  short8 ov;
  ov[0] = f2bf(v0.x * inv * g0.x);
  ov[1] = f2bf(v0.y * inv * g0.y);
  ov[2] = f2bf(v0.z * inv * g0.z);
  ov[3] = f2bf(v0.w * inv * g0.w);
  ov[4] = f2bf(v1.x * inv * g1v.x);
  ov[5] = f2bf(v1.y * inv * g1v.y);
  ov[6] = f2bf(v1.z * inv * g1v.z);
  ov[7] = f2bf(v1.w * inv * g1v.w);
  *((short8*)(o + (size_t)row * D_MODEL) + t) = ov;
}

// ---------------- fp32 -> bf16 convert (weights, one-time) ----------------
__global__ __launch_bounds__(256) void f2b_k(const float* __restrict__ src,
                                             short* __restrict__ dst, int n8) {
  int i = blockIdx.x * 256 + threadIdx.x;
  if (i >= n8) return;
  const float4* s4 = (const float4*)src + 2 * (size_t)i;
  float4 a = s4[0], b = s4[1];
  short8 o = { f2bf(a.x), f2bf(a.y), f2bf(a.z), f2bf(a.w),
               f2bf(b.x), f2bf(b.y), f2bf(b.z), f2bf(b.w) };
  *((short8*)dst + i) = o;
}

// ---------------- split-K combine: o = p0 + p1 + r (fp32) ----------------
__global__ __launch_bounds__(256) void combine_k(const float* p0, const float* p1,
                                                 const float* r, float* o, int n4) {
  int i = blockIdx.x * 256 + threadIdx.x;
  if (i >= n4) return;
  const float4 a = ((const float4*)p0)[i];
  const float4 b = ((const float4*)p1)[i];
  const float4 c = ((const float4*)r)[i];
  float4 d;
  d.x = a.x + b.x + c.x; d.y = a.y + b.y + c.y;
  d.z = a.z + b.z + c.z; d.w = a.w + b.w + c.w;
  ((float4*)o)[i] = d;
}

// ======== 256x256 minimal-sync double-buffer GEMM ========
// C[M,N] = A[M,K](bf16) * B[N,K](bf16)^T. 512 thr = 8 waves (2M x 4N), wave 128x64.
// LDS: As/Bs [slot][half][128x64], 128 KB, XOR-swizzled ((row&7)<<3 shorts) via
// pre-swizzled global source + swizzled ds_read. Slot discipline: tile T reads
// slot p=T&1 ONLY; tile T+1 staged entirely into slot q=p^1 (8 global_load_lds
// per wave) -> no intra-tile WAR hazard -> ONE vmcnt(0)+s_barrier per K-tile
// (loads waited on were issued a full tile earlier => no stall). Reads spread
// over 4 MFMA groups; compiler inserts fine-grained lgkmcnt; waves self-stagger
// so LDS fulfillment overlaps other waves' MFMA.
// EPI: 0 bf16; 1 GELU bf16; 2 +resid fp32; 3 plain fp32. SPLIT: split-K x2.
template<int EPI, int SPLIT>
__global__ __launch_bounds__(512, 2) void gemm256(const short* __restrict__ A,
                                                  const short* __restrict__ Bp,
                                                  void* Cv,
                                                  const float* __restrict__ resid,
                                                  int M, int N, int K,
                                                  int lda, int ldb, int nbx) {
  __shared__ __align__(16) short As[2][2][128 * 64];   // 64 KB
  __shared__ __align__(16) short Bs[2][2][128 * 64];   // 64 KB
  const int nk = K >> 6;
  const int cpx = gridDim.x >> 3;
  const int lin = (blockIdx.x & 7) * cpx + (blockIdx.x >> 3);
  const int bx = lin % nbx;
  int row2 = lin / nbx, by, ks = 0;
  if (SPLIT) { ks = row2 & 1; by = row2 >> 1; } else { by = row2; }
  const int m0 = bx * 256, n0 = by * 256;
  if (SPLIT) { A += (size_t)ks * K; Bp += (size_t)ks * K; }

  const int t = threadIdx.x, w = t >> 6, lane = t & 63, lr = lane & 15, lg = lane >> 4;
  const int wm = w >> 2, wn = w & 3;
  const unsigned aByte = (unsigned)(size_t)(const __attribute__((address_space(3))) short*)&As[0][0][0];
  const unsigned bByte = (unsigned)(size_t)(const __attribute__((address_space(3))) short*)&Bs[0][0][0];
  const unsigned wOff = (unsigned)(w * 1024);

  // staging geometry: thread t covers rows r and r+64 of a 128-row half, chunk c8
  const int r = t >> 3, c8 = t & 7;
  const int sw = (c8 ^ (r & 7)) << 3;                 // (r+64)&7 == r&7
  const short* pA0 = A  + (size_t)(m0 + r)       * lda + sw;
  const short* pA1 = A  + (size_t)(m0 + 128 + r) * lda + sw;
  const short* pB0 = Bp + (size_t)(n0 + r)       * ldb + sw;
  const short* pB1 = Bp + (size_t)(n0 + 128 + r) * ldb + sw;
  const size_t l64A = (size_t)64 * lda, l64B = (size_t)64 * ldb;

#define STAGE_TILE(tt, slotByteA, slotByteB) { \
    const short* a0_ = pA0 + (size_t)(tt) * 64; \
    STG(a0_, (slotByteA) + wOff);            STG(a0_ + l64A, (slotByteA) + 8192u + wOff); \
    const short* a1_ = pA1 + (size_t)(tt) * 64; \
    STG(a1_, (slotByteA) + 16384u + wOff);   STG(a1_ + l64A, (slotByteA) + 16384u + 8192u + wOff); \
    const short* b0_ = pB0 + (size_t)(tt) * 64; \
    STG(b0_, (slotByteB) + wOff);            STG(b0_ + l64B, (slotByteB) + 8192u + wOff); \
    const short* b1_ = pB1 + (size_t)(tt) * 64; \
    STG(b1_, (slotByteB) + 16384u + wOff);   STG(b1_ + l64B, (slotByteB) + 16384u + 8192u + wOff); }

  f32x4 acc[8][4];
  const f32x4 z4 = {0.f, 0.f, 0.f, 0.f};
  #pragma unroll
  for (int m = 0; m < 8; ++m)
    #pragma unroll
    for (int n = 0; n < 4; ++n) acc[m][n] = z4;

  // ---- prologue: stage tile 0 into slot 0; drain; barrier ----
  STAGE_TILE(0, aByte, bByte);
  asm volatile("s_waitcnt vmcnt(0)" ::: "memory");
  __builtin_amdgcn_s_barrier();

  for (int T = 0; T < nk; ++T) {
    const int p = T & 1, q = p ^ 1;

    // stage ALL of tile T+1 into slot q (untouched by tile-T readers)
    if (T + 1 < nk)
      STAGE_TILE(T + 1, aByte + (unsigned)q * 32768u, bByte + (unsigned)q * 32768u);

    // ---- group 1: B k0 + A m0-3 k0 ----
    short8 bk0[4], bk1[4], aA[4];
    #pragma unroll
    for (int n = 0; n < 4; ++n) {
      int br = wn * 64 + n * 16 + lr;
      const short* bp = &Bs[p][br >> 7][(br & 127) * 64];
      bk0[n] = *(const short8*)&bp[(lg * 8) ^ ((br & 7) << 3)];
    }
    #pragma unroll
    for (int m = 0; m < 4; ++m) {
      int ar = m * 16 + lr;
      aA[m] = *(const short8*)&As[p][wm][ar * 64 + ((lg * 8) ^ ((ar & 7) << 3))];
    }
    #pragma unroll
    for (int m = 0; m < 4; ++m)
      #pragma unroll
      for (int n = 0; n < 4; ++n) acc[m][n] = MF(aA[m], bk0[n], acc[m][n]);

    // ---- group 2: A m4-7 k0 ----
    short8 aB[4];
    #pragma unroll
    for (int m = 0; m < 4; ++m) {
      int ar = 64 + m * 16 + lr;
      aB[m] = *(const short8*)&As[p][wm][ar * 64 + ((lg * 8) ^ ((ar & 7) << 3))];
    }
    #pragma unroll
    for (int m = 0; m < 4; ++m)
      #pragma unroll
      for (int n = 0; n < 4; ++n) acc[m + 4][n] = MF(aB[m], bk0[n], acc[m + 4][n]);

    // ---- group 3: B k1 + A m0-3 k1 ----
    short8 aC[4];
    #pragma unroll
    for (int n = 0; n < 4; ++n) {
      int br = wn * 64 + n * 16 + lr;
      const short* bp = &Bs[p][br >> 7][(br & 127) * 64];
      bk1[n] = *(const short8*)&bp[(32 + lg * 8) ^ ((br & 7) << 3)];
    }
    #pragma unroll
    for (int m = 0; m < 4; ++m) {
      int ar = m * 16 + lr;
      aC[m] = *(const short8*)&As[p][wm][ar * 64 + ((32 + lg * 8) ^ ((ar & 7) << 3))];
    }
    #pragma unroll
    for (int m = 0; m < 4; ++m)
      #pragma unroll
      for (int n = 0; n < 4; ++n) acc[m][n] = MF(aC[m], bk1[n], acc[m][n]);

    // ---- group 4: A m4-7 k1 ----
    short8 aD[4];
    #pragma unroll
    for (int m = 0; m < 4; ++m) {
      int ar = 64 + m * 16 + lr;
      aD[m] = *(const short8*)&As[p][wm][ar * 64 + ((32 + lg * 8) ^ ((ar & 7) << 3))];
    }
    #pragma unroll
    for (int m = 0; m < 4; ++m)
      #pragma unroll
      for (int n = 0; n < 4; ++n) acc[m + 4][n] = MF(aD[m], bk1[n], acc[m + 4][n]);

    // ---- tile boundary: T+1's loads (issued a full tile ago) must be landed ----
    if (T + 1 < nk) {
      asm volatile("s_waitcnt vmcnt(0)" ::: "memory");
      __builtin_amdgcn_s_barrier();
    }
  }
#undef STAGE_TILE

  // ---- epilogue ----
  float* Cf = (float*)Cv;
  if (SPLIT) Cf += (size_t)ks * ((size_t)M * N);
  #pragma unroll
  for (int m = 0; m < 8; ++m)
    #pragma unroll
    for (int n = 0; n < 4; ++n)
      #pragma unroll
      for (int rr = 0; rr < 4; ++rr) {
        int row = m0 + wm * 128 + m * 16 + lg * 4 + rr;
        int col = n0 + wn * 64 + n * 16 + lr;
        size_t idx = (size_t)row * N + col;
        float vv = acc[m][n][rr];
        if (EPI == 0) {
          ((short*)Cv)[idx] = f2bf(vv);
        } else if (EPI == 1) {
          float gl = 0.5f * vv * (1.0f + erff(vv * 0.70710678118654752f));
          ((short*)Cv)[idx] = f2bf(gl);
        } else if (EPI == 2) {
          ((float*)Cv)[idx] = vv + resid[idx];
        } else {
          Cf[idx] = vv;
        }
      }
}

// ---------------- V transpose: qkv[.., v cols] -> vt[b][h][d][s] ----------------
__global__ __launch_bounds__(256) void vtrans(const short* __restrict__ QKV,
                                              short* __restrict__ VT) {
  const int st = blockIdx.x;   // s tile of 64
  const int bh = blockIdx.y;
  const int b = bh >> 4, h = bh & 15;
  const int t = threadIdx.x;
  __shared__ __align__(16) short T[64 * 128];
  const short* Vsrc = QKV + ((size_t)b * SEQ) * 6144 + 2 * D_MODEL + h * DK;
  {
    int r = t >> 4, c = (t & 15) * 8;
    #pragma unroll
    for (int i = 0; i < 4; ++i) {
      int rr = r + 16 * i;
      uint4 vv = *(const uint4*)(Vsrc + (size_t)(st * 64 + rr) * 6144 + c);
      *(uint4*)&T[rr * 128 + (c ^ (((rr >> 3) & 7) << 3))] = vv;
    }
  }
  __syncthreads();
  short* dst = VT + ((size_t)bh * DK) * SEQ + st * 64;
  {
    int c2 = (t & 7) * 8;
    #pragma unroll
    for (int i = 0; i < 4; ++i) {
      int d = (t >> 3) + 32 * i;
      short8 ov;
      #pragma unroll
      for (int j = 0; j < 8; ++j)
        ov[j] = T[(c2 + j) * 128 + (d ^ ((((c2 + j) >> 3) & 7) << 3))];
      *(short8*)(dst + (size_t)d * SEQ + c2) = ov;
    }
  }
}

// ---------------- Flash attention v3 (round-4 verified) ----------------
__global__ __launch_bounds__(512, 2) void attn3(const short* __restrict__ QKV,
                                                const short* __restrict__ VT,
                                                short* __restrict__ O) {
  const float SC = 0.12751743f;   // (1/sqrt(128)) * log2(e)
  const int a = blockIdx.x, bh = blockIdx.y;
  const int b = bh >> 4, h = bh & 15;
  const int t = threadIdx.x, w = t >> 6, lane = t & 63, lr = lane & 15, lg = lane >> 4;
  const short* Qp = QKV + ((size_t)b * SEQ) * 6144 + h * DK;
  const short* Kp = Qp + D_MODEL;
  const short* Vp = VT + ((size_t)bh * DK) * SEQ;   // [d][s]
  __shared__ __align__(16) short Ks[2][64 * 128];
  __shared__ __align__(16) short Vs[2][128 * 64];
  __shared__ __align__(16) short Ps[8][16][72];

  const int krr = t >> 4, kcc = (t & 15) * 8;
  const int vdd = t >> 3, vcc = (t & 7) * 8;
  const f32x4 z4 = {0.f, 0.f, 0.f, 0.f};

  for (int sub = 0; sub < 2; ++sub) {
    const int ts = sub ? (15 - a) : a;
    const int nt = 2 * ts + 2;
    const int qrow0 = ts * 128 + w * 16;

    short8 qf[4];
    #pragma unroll
    for (int ki = 0; ki < 4; ++ki)
      qf[ki] = *(const short8*)(Qp + (size_t)(qrow0 + lr) * 6144 + ki * 32 + lg * 8);

    f32x4 acc[8];
    #pragma unroll
    for (int nd = 0; nd < 8; ++nd) acc[nd] = z4;
    float mrow[4], lsum[4];
    #pragma unroll
    for (int r = 0; r < 4; ++r) { mrow[r] = -INFINITY; lsum[r] = 0.f; }

    uint4 krg[2], vrg[2];
    #pragma unroll
    for (int i = 0; i < 2; ++i) {
      krg[i] = *(const uint4*)(Kp + (size_t)(krr + 32 * i) * 6144 + kcc);
      vrg[i] = *(const uint4*)(Vp + (size_t)(vdd + 64 * i) * SEQ + vcc);
    }
    __syncthreads();
    #pragma unroll
    for (int i = 0; i < 2; ++i) {
      int r = krr + 32 * i;
      *(uint4*)&Ks[0][(r * 128 + kcc) ^ ((r & 7) << 3)] = krg[i];
      int d = vdd + 64 * i;
      *(uint4*)&Vs[0][(d * 64 + vcc) ^ ((d & 7) << 3)] = vrg[i];
    }
    __syncthreads();

    int cur = 0;
    for (int tt = 0; tt < nt; ++tt) {
      const bool pre = (tt + 1 < nt);
      if (pre) {
        #pragma unroll
        for (int i = 0; i < 2; ++i) {
          krg[i] = *(const uint4*)(Kp + (size_t)((tt + 1) * 64 + krr + 32 * i) * 6144 + kcc);
          vrg[i] = *(const uint4*)(Vp + (size_t)(vdd + 64 * i) * SEQ + (tt + 1) * 64 + vcc);
        }
      }

      f32x4 sf[4] = {z4, z4, z4, z4};
      #pragma unroll
      for (int ki = 0; ki < 4; ++ki) {
        #pragma unroll
        for (int nk = 0; nk < 4; ++nk) {
          int rr = nk * 16 + lr;
          short8 kf = *(const short8*)&Ks[cur][(rr * 128 + ki * 32 + lg * 8) ^ ((rr & 7) << 3)];
          sf[nk] = MF(qf[ki], kf, sf[nk]);
        }
      }

      const bool diag = (tt * 64 + 63 > qrow0);
      #pragma unroll
      for (int r = 0; r < 4; ++r) {
        int qg = qrow0 + lg * 4 + r;
        float s0 = sf[0][r] * SC, s1 = sf[1][r] * SC, s2 = sf[2][r] * SC, s3 = sf[3][r] * SC;
        if (diag) {
          int c0 = tt * 64 + lr;
          s0 = (c0      <= qg) ? s0 : -3.0e38f;
          s1 = (c0 + 16 <= qg) ? s1 : -3.0e38f;
          s2 = (c0 + 32 <= qg) ? s2 : -3.0e38f;
          s3 = (c0 + 48 <= qg) ? s3 : -3.0e38f;
        }
        float mx = fmaxf(fmaxf(s0, s1), fmaxf(s2, s3));
        mx = fmaxf(mx, __shfl_xor(mx, 1));
        mx = fmaxf(mx, __shfl_xor(mx, 2));
        mx = fmaxf(mx, __shfl_xor(mx, 4));
        mx = fmaxf(mx, __shfl_xor(mx, 8));
        float mnew = fmaxf(mrow[r], mx);
        float alpha = exp2f(mrow[r] - mnew);
        mrow[r] = mnew;
        float p0 = exp2f(s0 - mnew), p1 = exp2f(s1 - mnew),
              p2 = exp2f(s2 - mnew), p3 = exp2f(s3 - mnew);
        lsum[r] = lsum[r] * alpha + ((p0 + p1) + (p2 + p3));
        #pragma unroll
        for (int nd = 0; nd < 8; ++nd) acc[nd][r] *= alpha;
        short* pr = &Ps[w][lg * 4 + r][0];
        pr[lr]      = f2bf(p0);
        pr[16 + lr] = f2bf(p1);
        pr[32 + lr] = f2bf(p2);
        pr[48 + lr] = f2bf(p3);
      }
      asm volatile("s_waitcnt lgkmcnt(0)" ::: "memory");
      __builtin_amdgcn_sched_barrier(0);

      short8 pf0 = *(const short8*)&Ps[w][lr][lg * 8];
      short8 pf1 = *(const short8*)&Ps[w][lr][32 + lg * 8];
      #pragma unroll
      for (int nd = 0; nd < 8; ++nd) {
        int rr = nd * 16 + lr;
        short8 vf0 = *(const short8*)&Vs[cur][(rr * 64 + lg * 8) ^ ((rr & 7) << 3)];
        short8 vf1 = *(const short8*)&Vs[cur][(rr * 64 + 32 + lg * 8) ^ ((rr & 7) << 3)];
        acc[nd] = MF(pf0, vf0, acc[nd]);
        acc[nd] = MF(pf1, vf1, acc[nd]);
      }
      __syncthreads();
      if (pre) {
        #pragma unroll
        for (int i = 0; i < 2; ++i) {
          int r = krr + 32 * i;
          *(uint4*)&Ks[cur ^ 1][(r * 128 + kcc) ^ ((r & 7) << 3)] = krg[i];
          int d = vdd + 64 * i;
          *(uint4*)&Vs[cur ^ 1][(d * 64 + vcc) ^ ((d & 7) << 3)] = vrg[i];
        }
      }
      __syncthreads();
      cur ^= 1;
    }

    float inv[4];
    #pragma unroll
    for (int r = 0; r < 4; ++r) {
      float ls = lsum[r];
      ls += __shfl_xor(ls, 1);
      ls += __shfl_xor(ls, 2);
      ls += __shfl_xor(ls, 4);
      ls += __shfl_xor(ls, 8);
      inv[r] = 1.0f / ls;
    }
    #pragma unroll
    for (int nd = 0; nd < 8; ++nd)
      #pragma unroll
      for (int r = 0; r < 4; ++r) {
        int row = qrow0 + lg * 4 + r;
        O[(size_t)(b * SEQ + row) * D_MODEL + h * DK + nd * 16 + lr] = f2bf(acc[nd][r] * inv[r]);
      }
  }
}

// ======== FALLBACK PATH (round-2 verified kernels) ========
template<int EPI>
__global__ __launch_bounds__(256) void gemm_bt(const short* __restrict__ A,
                                               const float* __restrict__ B,
                                               void* Cv,
                                               const float* resid,
                                               int M, int N, int K) {
  __shared__ __align__(16) short As[128][72];
  __shared__ __align__(16) short Bs[128][72];
  const int t = threadIdx.x;
  const int m0 = blockIdx.x * 128, n0 = blockIdx.y * 128;
  const int wave = t >> 6, lane = t & 63, lr = lane & 15, lg = lane >> 4;
  const int wr = (wave >> 1) * 64, wc = (wave & 1) * 64;

  f32x4 acc[4][4];
  const f32x4 z4 = {0.f, 0.f, 0.f, 0.f};
  #pragma unroll
  for (int m = 0; m < 4; ++m)
    #pragma unroll
    for (int n = 0; n < 4; ++n) acc[m][n] = z4;

  int ar[4], ac[4];
  #pragma unroll
  for (int i = 0; i < 4; ++i) { int u = t + 256*i; ar[i] = u >> 3; ac[i] = (u & 7) * 8; }

  for (int k0 = 0; k0 < K; k0 += 64) {
    #pragma unroll
    for (int i = 0; i < 4; ++i) {
      uint4 va = *(const uint4*)(A + (size_t)(m0 + ar[i]) * K + k0 + ac[i]);
      *(uint4*)&As[ar[i]][ac[i]] = va;
    }
    #pragma unroll
    for (int i = 0; i < 4; ++i) {
      const float4* bp = (const float4*)(B + (size_t)(n0 + ar[i]) * K + k0 + ac[i]);
      float4 b0 = bp[0], b1 = bp[1];
      short8 pb = { f2bf(b0.x), f2bf(b0.y), f2bf(b0.z), f2bf(b0.w),
                    f2bf(b1.x), f2bf(b1.y), f2bf(b1.z), f2bf(b1.w) };
      *(short8*)&Bs[ar[i]][ac[i]] = pb;
    }
    __syncthreads();
    #pragma unroll
    for (int kk = 0; kk < 64; kk += 32) {
      short8 af[4], bfr[4];
      #pragma unroll
      for (int m = 0; m < 4; ++m) af[m]  = *(const short8*)&As[wr + m*16 + lr][kk + lg*8];
      #pragma unroll
      for (int n = 0; n < 4; ++n) bfr[n] = *(const short8*)&Bs[wc + n*16 + lr][kk + lg*8];
      #pragma unroll
      for (int m = 0; m < 4; ++m)
        #pragma unroll
        for (int n = 0; n < 4; ++n)
          acc[m][n] = MF(af[m], bfr[n], acc[m][n]);
    }
    __syncthreads();
  }

  #pragma unroll
  for (int m = 0; m < 4; ++m)
    #pragma unroll
    for (int n = 0; n < 4; ++n)
      #pragma unroll
      for (int r = 0; r < 4; ++r) {
        int row = m0 + wr + m*16 + lg*4 + r;
        int col = n0 + wc + n*16 + lr;
        size_t idx = (size_t)row * N + col;
        float vv = acc[m][n][r];
        if (EPI == 0) {
          ((short*)Cv)[idx] = f2bf(vv);
        } else if (EPI == 1) {
          float gl = 0.5f * vv * (1.0f + erff(vv * 0.70710678118654752f));
          ((short*)Cv)[idx] = f2bf(gl);
        } else {
          ((float*)Cv)[idx] = vv + resid[idx];
        }
      }
}

__global__ __launch_bounds__(256) void attn_k(const short* __restrict__ Q,
                                              const short* __restrict__ K,
                                              const short* __restrict__ V,
                                              short* __restrict__ O) {
  const float scale = 0.08838834764831845f;
  const int qt = blockIdx.x;
  const int bh = blockIdx.y;
  const int b = bh >> 4, h = bh & 15;
  const size_t base = ((size_t)b * SEQ) * D_MODEL + (size_t)h * DK;
  const int t = threadIdx.x, wave = t >> 6, lane = t & 63, lr = lane & 15, lg = lane >> 4;

  __shared__ __align__(16) short Ks[32][136];
  __shared__ __align__(16) short Vt[128][40];
  __shared__ __align__(16) short Ps[4][32][40];

  const int qrow0 = qt * 128 + wave * 32;
  short8 qf[2][4];
  #pragma unroll
  for (int mq = 0; mq < 2; ++mq)
    #pragma unroll
    for (int ki = 0; ki < 4; ++ki)
      qf[mq][ki] = *(const short8*)(Q + base + (size_t)(qrow0 + mq*16 + lr) * D_MODEL + ki*32 + lg*8);

  f32x4 acc[2][8];
  const f32x4 z4 = {0.f, 0.f, 0.f, 0.f};
  #pragma unroll
  for (int mq = 0; mq < 2; ++mq)
    #pragma unroll
    for (int nd = 0; nd < 8; ++nd) acc[mq][nd] = z4;
  float mrow[2][4], lsum[2][4];
  #pragma unroll
  for (int mq = 0; mq < 2; ++mq)
    #pragma unroll
    for (int r = 0; r < 4; ++r) { mrow[mq][r] = -INFINITY; lsum[mq][r] = 0.f; }

  const int lastt = qt * 4 + 3;
  for (int tt = 0; tt <= lastt; ++tt) {
    #pragma unroll
    for (int i = 0; i < 2; ++i) {
      int u = t + 256*i; int r = u >> 4; int c = (u & 15) * 8;
      *(uint4*)&Ks[r][c] = *(const uint4*)(K + base + (size_t)(tt*32 + r) * D_MODEL + c);
      uint4 vv = *(const uint4*)(V + base + (size_t)(tt*32 + r) * D_MODEL + c);
      const short* sv = (const short*)&vv;
      #pragma unroll
      for (int j = 0; j < 8; ++j) Vt[c + j][r] = sv[j];
    }
    __syncthreads();
    if (tt <= qt * 4 + wave) {
      f32x4 sf[2][2] = {{z4, z4}, {z4, z4}};
      #pragma unroll
      for (int ki = 0; ki < 4; ++ki) {
        short8 kf0 = *(const short8*)&Ks[lr][ki*32 + lg*8];
        short8 kf1 = *(const short8*)&Ks[16 + lr][ki*32 + lg*8];
        sf[0][0] = MF(qf[0][ki], kf0, sf[0][0]);
        sf[0][1] = MF(qf[0][ki], kf1, sf[0][1]);
        sf[1][0] = MF(qf[1][ki], kf0, sf[1][0]);
        sf[1][1] = MF(qf[1][ki], kf1, sf[1][1]);
      }
      #pragma unroll
      for (int mq = 0; mq < 2; ++mq) {
        #pragma unroll
        for (int r = 0; r < 4; ++r) {
          int qg = qrow0 + mq*16 + lg*4 + r;
          float s0 = sf[mq][0][r] * scale;
          float s1 = sf[mq][1][r] * scale;
          if (tt*32 + lr > qg)       s0 = -INFINITY;
          if (tt*32 + 16 + lr > qg)  s1 = -INFINITY;
          float mx = fmaxf(s0, s1);
          mx = fmaxf(mx, __shfl_xor(mx, 1));
          mx = fmaxf(mx, __shfl_xor(mx, 2));
          mx = fmaxf(mx, __shfl_xor(mx, 4));
          mx = fmaxf(mx, __shfl_xor(mx, 8));
          float mnew = fmaxf(mrow[mq][r], mx);
          float alpha = __expf(mrow[mq][r] - mnew);
          mrow[mq][r] = mnew;
          float p0 = __expf(s0 - mnew);
          float p1 = __expf(s1 - mnew);
          float ps = p0 + p1;
          ps += __shfl_xor(ps, 1);
          ps += __shfl_xor(ps, 2);
          ps += __shfl_xor(ps, 4);
          ps += __shfl_xor(ps, 8);
          lsum[mq][r] = lsum[mq][r] * alpha + ps;
          #pragma unroll
          for (int nd = 0; nd < 8; ++nd) acc[mq][nd][r] *= alpha;
          Ps[wave][mq*16 + lg*4 + r][lr]      = f2bf(p0);
          Ps[wave][mq*16 + lg*4 + r][16 + lr] = f2bf(p1);
        }
      }
      asm volatile("s_waitcnt lgkmcnt(0)" ::: "memory");
      short8 pf0 = *(const short8*)&Ps[wave][lr][lg*8];
      short8 pf1 = *(const short8*)&Ps[wave][16 + lr][lg*8];
      #pragma unroll
      for (int nd = 0; nd < 8; ++nd) {
        short8 vf = *(const short8*)&Vt[nd*16 + lr][lg*8];
        acc[0][nd] = MF(pf0, vf, acc[0][nd]);
        acc[1][nd] = MF(pf1, vf, acc[1][nd]);
      }
    }
    __syncthreads();
  }

  #pragma unroll
  for (int mq = 0; mq < 2; ++mq)
    #pragma unroll
    for (int nd = 0; nd < 8; ++nd)
      #pragma unroll
      for (int r = 0; r < 4; ++r) {
        int row = qrow0 + mq*16 + lg*4 + r;
        O[base + (size_t)row * D_MODEL + nd*16 + lr] = f2bf(acc[mq][nd][r] / lsum[mq][r]);
      }
}

// ---------------- launch ----------------
extern "C" void kernel_launch(void* const* d_in, const int* in_sizes, int n_in,
                              void* d_out, int out_size, void* d_ws, size_t ws_size,
                              hipStream_t stream) {
  const float* x  = (const float*)d_in[0];
  const float* wq = (const float*)d_in[1];
  const float* wk = (const float*)d_in[2];
  const float* wv = (const float*)d_in[3];
  const float* wo = (const float*)d_in[4];
  const float* w1 = (const float*)d_in[5];
  const float* w2 = (const float*)d_in[6];
  const float* g1 = (const float*)d_in[7];
  const float* g2 = (const float*)d_in[8];
  float* out = (float*)d_out;
  char* ws = (char*)d_ws;

  const size_t NEED = (size_t)192 << 20;
  if (ws_size >= NEED) {
    // fast path layout (192 MiB):
    //   [0,24M) wqkv | [24,32M) wo | [32,64M) w1 | [64,96M) w2   (bf16 weights)
    //   [96,144M) qkv | [144,160M) vt | [160,176M) ab | [176,192M) xn
    //   FFN phase: hb = [96,160M); FFN2 split-K partials = [160,192M) (ab/xn dead)
    short* wqkv = (short*)(ws);
    short* wo_b = (short*)(ws + ((size_t)24 << 20));
    short* w1_b = (short*)(ws + ((size_t)32 << 20));
    short* w2_b = (short*)(ws + ((size_t)64 << 20));
    short* qkv  = (short*)(ws + ((size_t)96 << 20));
    short* vt   = (short*)(ws + ((size_t)144 << 20));
    short* ab   = (short*)(ws + ((size_t)160 << 20));
    short* xn   = (short*)(ws + ((size_t)176 << 20));
    short* hb   = (short*)(ws + ((size_t)96 << 20));
    float* pf   = (float*)(ws + ((size_t)160 << 20));   // 2x 32MB fp32 partials

    const int NW = D_MODEL * D_MODEL / 8;
    f2b_k<<<(NW + 255) / 256, 256, 0, stream>>>(wq, wqkv,                   NW);
    f2b_k<<<(NW + 255) / 256, 256, 0, stream>>>(wk, wqkv + (size_t)D_MODEL * D_MODEL,     NW);
    f2b_k<<<(NW + 255) / 256, 256, 0, stream>>>(wv, wqkv + (size_t)2 * D_MODEL * D_MODEL, NW);
    f2b_k<<<(NW + 255) / 256, 256, 0, stream>>>(wo, wo_b, NW);
    const int NF = DFF * D_MODEL / 8;
    f2b_k<<<(NF + 255) / 256, 256, 0, stream>>>(w1, w1_b, NF);
    f2b_k<<<(NF + 255) / 256, 256, 0, stream>>>(w2, w2_b, NF);

    rmsnorm_k<<<MROWS, 256, 0, stream>>>(x, g1, xn);
    // QKV: 16x24 = 384 blocks
    gemm256<0,0><<<dim3(16 * 24), 512, 0, stream>>>(xn, wqkv, qkv, nullptr,
                                                    MROWS, 6144, D_MODEL, D_MODEL, D_MODEL, 16);
    vtrans<<<dim3(SEQ/64, BATCH*NHEAD), 256, 0, stream>>>(qkv, vt);
    attn3<<<dim3(8, BATCH*NHEAD), 512, 0, stream>>>(qkv, vt, ab);
    // o-proj: 16x8 = 128 blocks, +resid
    gemm256<2,0><<<dim3(16 * 8), 512, 0, stream>>>(ab, wo_b, out, x,
                                                   MROWS, D_MODEL, D_MODEL, D_MODEL, D_MODEL, 16);
    rmsnorm_k<<<MROWS, 256, 0, stream>>>(out, g2, xn);
    // FFN1: 16x32 = 512 blocks, GELU
    gemm256<1,0><<<dim3(16 * 32), 512, 0, stream>>>(xn, w1_b, hb, nullptr,
                                                    MROWS, DFF, D_MODEL, D_MODEL, D_MODEL, 16);
    // FFN2: split-K x2 in one dispatch (16x8x2 = 256 blocks), then combine with resid
    gemm256<3,1><<<dim3(16 * 8 * 2), 512, 0, stream>>>(hb, w2_b, pf, nullptr,
                                                       MROWS, D_MODEL, DFF / 2, DFF, DFF, 16);
    const int N4 = MROWS * D_MODEL / 4;
    combine_k<<<(N4 + 255) / 256, 256, 0, stream>>>(pf, pf + (size_t)MROWS * D_MODEL, out, out, N4);
  } else {
    // fallback: round-2 verified path (80 MiB)
    short* qb = (short*)(ws + ((size_t)0  << 20));
    short* kb = (short*)(ws + ((size_t)16 << 20));
    short* vb = (short*)(ws + ((size_t)32 << 20));
    short* ab = (short*)(ws + ((size_t)48 << 20));
    short* xn = (short*)(ws + ((size_t)64 << 20));
    short* hb = (short*)(ws + ((size_t)0  << 20));

    dim3 gproj(MROWS / 128, D_MODEL / 128);
    rmsnorm_k<<<MROWS, 256, 0, stream>>>(x, g1, xn);
    gemm_bt<0><<<gproj, 256, 0, stream>>>(xn, wq, qb, nullptr, MROWS, D_MODEL, D_MODEL);
    gemm_bt<0><<<gproj, 256, 0, stream>>>(xn, wk, kb, nullptr, MROWS, D_MODEL, D_MODEL);
    gemm_bt<0><<<gproj, 256, 0, stream>>>(xn, wv, vb, nullptr, MROWS, D_MODEL, D_MODEL);
    attn_k<<<dim3(SEQ / 128, BATCH * NHEAD), 256, 0, stream>>>(qb, kb, vb, ab);
    gemm_bt<2><<<gproj, 256, 0, stream>>>(ab, wo, out, x, MROWS, D_MODEL, D_MODEL);
    rmsnorm_k<<<MROWS, 256, 0, stream>>>(out, g2, xn);
    for (int half = 0; half < 2; ++half) {
      const short* xh = xn  + (size_t)half * 2048 * D_MODEL;
      float*       oh = out + (size_t)half * 2048 * D_MODEL;
      gemm_bt<1><<<dim3(2048 / 128, DFF / 128), 256, 0, stream>>>(xh, w1, hb, nullptr, 2048, DFF, D_MODEL);
      gemm_bt<2><<<dim3(2048 / 128, D_MODEL / 128), 256, 0, stream>>>(hb, w2, oh, oh, 2048, D_MODEL, DFF);
    }
  }
}